// Round 15
// baseline (816.690 us; speedup 1.0000x reference)
//
#include <hip/hip_runtime.h>

// bPC SNN forward, 16 steps, B=128, dims 2048/4096/4096/512.
// v21: phase1 weights stored/staged as fp8 e4m3 (transposed copies W0t8/W1t8/
// V1t8/V2t8), dequantized to bf16 IN REGISTERS at MFMA time (exact: e4m3 is
// a subset of bf16). Rationale: both phases sit on the ~30-40 B/cyc per-CU
// LDS-DMA ingress wall; only byte reduction helps. Phase2 already consumes
// these weights as fp8 and passes at absmax 0.0625 -> same quantization class.
// z0 per-CU staged bytes 1.57 -> 1.18 MB; wprep writes -44MB. NOT bit-identical
// (W quantized); errors remain bf16. phase2 = v18, wprep = v20 structure.

#define DEVINL __device__ __forceinline__

using bf16x8 = __attribute__((ext_vector_type(8))) __bf16;
using f32x4  = __attribute__((ext_vector_type(4))) float;
using f32x2  = __attribute__((ext_vector_type(2))) float;
using i32x4  = __attribute__((ext_vector_type(4))) int;
typedef unsigned char uchar;

static constexpr int BB = 128;
static constexpr int D0 = 2048, D1 = 4096, D2 = 4096, D3 = 512;
static constexpr int NSTEPS = 16;

struct Ctx {
  const float *x, *y, *W0, *W1, *W2, *V0, *V1, *V2;
  float *v1, *j1, *r1, *tr1, *v2, *j2, *r2, *tr2;
  float *zd, *zl, *xV0T, *yW2T;
  __bf16 *x_bf, *y_bf, *eg0_bf, *eg1_bf, *ed2_bf, *ed3_bf;
  uchar *s1_f8, *s2_f8, *WA8, *WB8;            // fp8 spikes + stacked fp8 weights (phase2)
  uchar *W0t8, *W1t8, *V1t8, *V2t8;            // fp8 TRANSPOSED weights (phase1)
  __bf16 *V0n, *W2n;                           // bf16 (precomp only)
  float *out;
};

DEVINL void gload16(const void* g, void* l) {
  __builtin_amdgcn_global_load_lds(
      (const __attribute__((address_space(1))) void*)g,
      (__attribute__((address_space(3))) void*)l, 16, 0, 0);
}
DEVINL uint32_t lds_off(const void* p) {
  return (uint32_t)(uintptr_t)(__attribute__((address_space(3))) const void*)p;
}
DEVINL bf16x8 dsr128(uint32_t addr) {
  i32x4 r;
  asm volatile("ds_read_b128 %0, %1" : "=v"(r) : "v"(addr));
  return __builtin_bit_cast(bf16x8, r);
}
DEVINL long dsr64(uint32_t addr) {
  long r;
  asm volatile("ds_read_b64 %0, %1" : "=v"(r) : "v"(addr));
  return r;
}
// 8 fp8 e4m3 bytes -> 8 bf16 (exact embedding)
DEVINL bf16x8 cvtw(long v) {
  int lo = (int)(v & 0xffffffffL);
  int hi = (int)(((unsigned long long)v) >> 32);
  f32x2 p0 = __builtin_amdgcn_cvt_pk_f32_fp8(lo, false);
  f32x2 p1 = __builtin_amdgcn_cvt_pk_f32_fp8(lo, true);
  f32x2 p2 = __builtin_amdgcn_cvt_pk_f32_fp8(hi, false);
  f32x2 p3 = __builtin_amdgcn_cvt_pk_f32_fp8(hi, true);
  bf16x8 r;
  r[0] = (__bf16)p0[0]; r[1] = (__bf16)p0[1];
  r[2] = (__bf16)p1[0]; r[3] = (__bf16)p1[1];
  r[4] = (__bf16)p2[0]; r[5] = (__bf16)p2[1];
  r[6] = (__bf16)p3[0]; r[7] = (__bf16)p3[1];
  return r;
}

// ================= engines =================
struct Seg { const __bf16* A; unsigned ldA; const __bf16* W; unsigned ldW; int iters; };
struct SPtr { const __bf16 *a0, *a1, *w; };
struct Seg8 { const __bf16* A; unsigned ldA; const uchar* W; unsigned ldW; int iters; };
struct SP8 { const __bf16* a; const uchar* w; };

DEVINL SPtr mkptr(const Seg& s, int t) {
  int r = t >> 3;
  int u = ((t & 7) ^ (r & 7)) * 8;
  SPtr p;
  p.a0 = s.A + (size_t)r * s.ldA + u;
  p.a1 = s.A + (size_t)(r + 32) * s.ldA + u;
  p.w  = s.W + (size_t)r * s.ldW + u;
  return p;
}
DEVINL SP8 mkptr8(const Seg8& s, int t) {
  int r = t >> 3;
  int ue = ((t & 7) ^ (r & 7)) * 8;    // elems (A, bf16, 16B)
  int ub = ((t & 7) ^ (r & 7)) * 16;   // bytes (W, fp8, 16B)
  SP8 p;
  p.a = s.A + (size_t)r * s.ldA + ue;
  p.w = s.W + (size_t)r * s.ldW + ub;
  return p;
}

// ---- BK=64 engine (precomp, 256 thr, bf16 W) ----
DEVINL void run_gemm(const Seg* segs, int nIter, __bf16* lsA, __bf16* lsW,
                     int t, int wm, int wn, int l16, int lg, f32x4* acc) {
  const int seg0it = segs[0].iters;
  SPtr p = mkptr(segs[0], t);
  int nxt = 0;
  auto stage = [&](int s) {
    __bf16* bA = lsA + (s & 3) * 4096;
    __bf16* bW = lsW + (s & 3) * 2048;
    gload16(p.a0, bA + t * 8);
    gload16(p.a1, bA + 2048 + t * 8);
    gload16(p.w,  bW + t * 8);
    p.a0 += 64; p.a1 += 64; p.w += 64;
    if (++nxt == seg0it) p = mkptr(segs[1], t);
  };

  const int x7 = l16 & 7;
  uint32_t aB = lds_off(lsA), wB = lds_off(lsW);
  uint32_t aAd[2][2], wAd[2];
#pragma unroll
  for (int mt = 0; mt < 2; ++mt)
#pragma unroll
    for (int ks = 0; ks < 2; ++ks)
      aAd[mt][ks] = aB + (uint32_t)(wm * 32 + mt * 16 + l16) * 128u
                       + (uint32_t)(((ks * 4 + lg) ^ x7) * 16);
#pragma unroll
  for (int ks = 0; ks < 2; ++ks)
    wAd[ks] = wB + (uint32_t)(wn * 16 + l16) * 128u
                 + (uint32_t)(((ks * 4 + lg) ^ x7) * 16);

  auto compute = [&](int i) {
    uint32_t oa = (uint32_t)(i & 3) * 8192u, ow = (uint32_t)(i & 3) * 4096u;
    bf16x8 a00 = dsr128(aAd[0][0] + oa);
    bf16x8 a01 = dsr128(aAd[0][1] + oa);
    bf16x8 a10 = dsr128(aAd[1][0] + oa);
    bf16x8 a11 = dsr128(aAd[1][1] + oa);
    bf16x8 b0  = dsr128(wAd[0] + ow);
    bf16x8 b1  = dsr128(wAd[1] + ow);
    asm volatile("s_waitcnt lgkmcnt(0)" ::: "memory");
    __builtin_amdgcn_sched_barrier(0);
    __builtin_amdgcn_s_setprio(1);
    acc[0] = __builtin_amdgcn_mfma_f32_16x16x32_bf16(a00, b0, acc[0], 0, 0, 0);
    acc[1] = __builtin_amdgcn_mfma_f32_16x16x32_bf16(a10, b0, acc[1], 0, 0, 0);
    acc[0] = __builtin_amdgcn_mfma_f32_16x16x32_bf16(a01, b1, acc[0], 0, 0, 0);
    acc[1] = __builtin_amdgcn_mfma_f32_16x16x32_bf16(a11, b1, acc[1], 0, 0, 0);
    __builtin_amdgcn_s_setprio(0);
  };

  stage(0); stage(1); stage(2);
  for (int i = 0; i < nIter - 3; ++i) {
    asm volatile("s_waitcnt vmcnt(6)" ::: "memory");
    __builtin_amdgcn_s_barrier();
    stage(i + 3);
    compute(i);
  }
  asm volatile("s_waitcnt vmcnt(6)" ::: "memory");
  __builtin_amdgcn_s_barrier();
  compute(nIter - 3);
  asm volatile("s_waitcnt vmcnt(3)" ::: "memory");
  __builtin_amdgcn_s_barrier();
  compute(nIter - 2);
  asm volatile("s_waitcnt vmcnt(0)" ::: "memory");
  __builtin_amdgcn_s_barrier();
  compute(nIter - 1);
}

// ---- BK=128 engine, 512 threads, fp8 W (phase1 v21) ----
// A: bf16 [64 rows][128 elems] per buf (16KB), 2 DMAs/stage.
// W: fp8  [64 rows][128 B]    per buf ( 8KB), 1 DMA/stage.
// Swizzle W: store unit (t&7) holds global unit (t&7)^(r&7); read unit for
// global j is j^(rw&7). Frag(h,ks): j = h*4+ks*2+(lg>>1), intra (lg&1)*8.
DEVINL void run_gemm128w8(const Seg8* segs, int nIter, __bf16* lsA, uchar* lsW8,
                          int t, int wm, int wn, int l16, int lg, f32x4* acc) {
  const int seg0it = segs[0].iters;   // in BK=128 units
  SP8 p = mkptr8(segs[0], t);
  int nxt = 0;
  auto stage = [&](int buf) {
    __bf16* bA = lsA + buf * 8192;
    uchar*  bW = lsW8 + buf * 8192;
    gload16(p.a,      bA + t * 8);          // K half0, rows 0..63
    gload16(p.a + 64, bA + 4096 + t * 8);   // K half1
    gload16(p.w,      bW + t * 16);         // full BK fp8 row
    p.a += 128; p.w += 128;
    if (++nxt == seg0it) p = mkptr8(segs[1], t);
  };

  const int x7 = l16 & 7;
  uint32_t aB = lds_off(lsA), wB = lds_off(lsW8);
  uint32_t aAd[2][2], wAd8[2][2];
#pragma unroll
  for (int mt = 0; mt < 2; ++mt)
#pragma unroll
    for (int ks = 0; ks < 2; ++ks)
      aAd[mt][ks] = aB + (uint32_t)(wm * 32 + mt * 16 + l16) * 128u
                       + (uint32_t)(((ks * 4 + lg) ^ x7) * 16);
  {
    int rw = wn * 16 + l16;
#pragma unroll
    for (int h = 0; h < 2; ++h)
#pragma unroll
      for (int ks = 0; ks < 2; ++ks) {
        int j = h * 4 + ks * 2 + (lg >> 1);
        wAd8[h][ks] = wB + (uint32_t)rw * 128u
                    + (uint32_t)(((j ^ (rw & 7)) * 16) + (lg & 1) * 8);
      }
  }

  auto compute = [&](int buf) {
    uint32_t oa = (uint32_t)buf * 16384u, ow = (uint32_t)buf * 8192u;
    bf16x8 a00 = dsr128(aAd[0][0] + oa);
    bf16x8 a01 = dsr128(aAd[0][1] + oa);
    bf16x8 a10 = dsr128(aAd[1][0] + oa);
    bf16x8 a11 = dsr128(aAd[1][1] + oa);
    bf16x8 c00 = dsr128(aAd[0][0] + oa + 8192);
    bf16x8 c01 = dsr128(aAd[0][1] + oa + 8192);
    bf16x8 c10 = dsr128(aAd[1][0] + oa + 8192);
    bf16x8 c11 = dsr128(aAd[1][1] + oa + 8192);
    long w00 = dsr64(wAd8[0][0] + ow);
    long w01 = dsr64(wAd8[0][1] + ow);
    long w10 = dsr64(wAd8[1][0] + ow);
    long w11 = dsr64(wAd8[1][1] + ow);
    asm volatile("s_waitcnt lgkmcnt(0)" ::: "memory");
    __builtin_amdgcn_sched_barrier(0);
    bf16x8 b0 = cvtw(w00);
    bf16x8 b1 = cvtw(w01);
    bf16x8 d0 = cvtw(w10);
    bf16x8 d1 = cvtw(w11);
    __builtin_amdgcn_s_setprio(1);
    acc[0] = __builtin_amdgcn_mfma_f32_16x16x32_bf16(a00, b0, acc[0], 0, 0, 0);
    acc[1] = __builtin_amdgcn_mfma_f32_16x16x32_bf16(a10, b0, acc[1], 0, 0, 0);
    acc[0] = __builtin_amdgcn_mfma_f32_16x16x32_bf16(a01, b1, acc[0], 0, 0, 0);
    acc[1] = __builtin_amdgcn_mfma_f32_16x16x32_bf16(a11, b1, acc[1], 0, 0, 0);
    acc[0] = __builtin_amdgcn_mfma_f32_16x16x32_bf16(c00, d0, acc[0], 0, 0, 0);
    acc[1] = __builtin_amdgcn_mfma_f32_16x16x32_bf16(c10, d0, acc[1], 0, 0, 0);
    acc[0] = __builtin_amdgcn_mfma_f32_16x16x32_bf16(c01, d1, acc[0], 0, 0, 0);
    acc[1] = __builtin_amdgcn_mfma_f32_16x16x32_bf16(c11, d1, acc[1], 0, 0, 0);
    __builtin_amdgcn_s_setprio(0);
  };

  stage(0); stage(1);
  int cur = 0, nx = 2;
  for (int i = 0; i < nIter - 2; ++i) {
    asm volatile("s_waitcnt vmcnt(3)" ::: "memory");
    __builtin_amdgcn_s_barrier();
    stage(nx);
    compute(cur);
    cur = (cur == 2) ? 0 : cur + 1;
    nx  = (nx == 2) ? 0 : nx + 1;
  }
  asm volatile("s_waitcnt vmcnt(3)" ::: "memory");
  __builtin_amdgcn_s_barrier();
  compute(cur);
  cur = (cur == 2) ? 0 : cur + 1;
  asm volatile("s_waitcnt vmcnt(0)" ::: "memory");
  __builtin_amdgcn_s_barrier();
  compute(cur);
}

// ================= phase1 v21 (bf16 A x fp8 W, 64x64, 512 thr) =================

__global__ __launch_bounds__(512, 1) void phase1_v21(Ctx c, float edsc) {
  __shared__ __align__(16) __bf16 lsA[3][8192];   // 48KB
  __shared__ __align__(128) uchar lsW8[3][8192];  // 24KB
  int t = threadIdx.x, w = t >> 6, l = t & 63;
  int l16 = l & 15, lg = l >> 4, wm = w >> 2, wn = w & 3;
  int bx = blockIdx.x;
  int z = bx >> 7, idx = bx & 127;
  int mh = idx >> 6, n0 = (idx & 63) * 64;
  f32x4 acc[2];
  f32x4 z4 = {0.f, 0.f, 0.f, 0.f};
  acc[0] = z4; acc[1] = z4;

  Seg8 segs[2]; int nIter, N;
  float *v, *j, *rf, *tr; const float* aux; const __bf16* buf; uchar* sf8;
  if (z == 0) {
    segs[0] = { c.ed2_bf + (size_t)mh * 64 * D2, (unsigned)D2, c.V1t8 + (size_t)n0 * D2, (unsigned)D2, 32 };
    segs[1] = { c.eg0_bf + (size_t)mh * 64 * D0, (unsigned)D0, c.W0t8 + (size_t)n0 * D0, (unsigned)D0, 16 };
    nIter = 48; N = D1;
    v = c.v1; j = c.j1; rf = c.r1; tr = c.tr1; buf = c.eg1_bf; aux = c.xV0T; sf8 = c.s1_f8;
  } else {
    segs[0] = { c.ed3_bf + (size_t)mh * 64 * D3, (unsigned)D3, c.V2t8 + (size_t)n0 * D3, (unsigned)D3, 4 };
    segs[1] = { c.eg1_bf + (size_t)mh * 64 * D1, (unsigned)D1, c.W1t8 + (size_t)n0 * D1, (unsigned)D1, 32 };
    nIter = 36; N = D2;
    v = c.v2; j = c.j2; rf = c.r2; tr = c.tr2; buf = c.ed2_bf; aux = c.yW2T; sf8 = c.s2_f8;
  }

  run_gemm128w8(segs, nIter, &lsA[0][0], &lsW8[0][0], t, wm, wn, l16, lg, acc);

  int n = n0 + wn * 16 + l16;
#pragma unroll
  for (int mt = 0; mt < 2; ++mt) {
#pragma unroll
    for (int r = 0; r < 4; ++r) {
      int b = mh * 64 + wm * 32 + mt * 16 + lg * 4 + r;
      size_t idx2 = (size_t)b * N + n;
      float to = tr[idx2];
      float ti = acc[mt][r] - (float)buf[idx2] - edsc * (to - aux[idx2]);
      float jo = j[idx2];
      float jn = jo + 0.1f * (ti - jo);
      float ro = rf[idx2];
      float vo = v[idx2];
      bool refr = ro > 0.0f;
      float vn = refr ? vo : (vo + 0.05f * (jn - vo));
      float sp = (!refr && vn > 1.0f) ? 1.0f : 0.0f;
      if (sp != 0.0f) vn = 0.0f;
      float rn = fmaxf(ro - 1.0f, 0.0f);
      if (sp != 0.0f) rn = 2.0f;
      float tn = to - 0.05f * to + sp;
      v[idx2] = vn; j[idx2] = jn; rf[idx2] = rn; tr[idx2] = tn;
      sf8[idx2] = (sp != 0.0f) ? (uchar)0x38 : (uchar)0;  // fp8 e4m3: 1.0 / 0.0 exact
    }
  }
}

// ================= phase2 v18 (fp8, 128B segments, 512 threads / 8 waves) =================

__global__ __launch_bounds__(512, 2) void phase2_v18(Ctx c) {
  __shared__ __align__(128) uchar lsA[4][8192];
  __shared__ __align__(128) uchar lsW[4][8192];
  int t = threadIdx.x, w = t >> 6, l = t & 63;
  int l16 = l & 15, lg = l >> 4, wm = w >> 2, wn = w & 3;
  int g = blockIdx.x, mh = blockIdx.y;

  const uchar *A, *W; int n0; bool isA;
  if (g < 96) { isA = true;  A = c.s1_f8 + (size_t)mh * 64 * D1; W = c.WA8 + (size_t)g * 64 * 4096;        n0 = g * 64; }
  else        { isA = false; A = c.s2_f8 + (size_t)mh * 64 * D2; W = c.WB8 + (size_t)(g - 96) * 64 * 4096; n0 = (g - 96) * 64; }

  f32x4 acc[2];
  f32x4 z4 = {0.f, 0.f, 0.f, 0.f};
  acc[0] = z4; acc[1] = z4;

  int row8 = t >> 3, u8 = t & 7;            // row8 0..63 (512 thr)
  int su8 = (u8 ^ ((row8 >> 1) & 7)) * 16;
  const uchar* pA = A + (size_t)row8 * 4096 + su8;
  const uchar* pW = W + (size_t)row8 * 4096 + su8;
  uchar* dA = &lsA[0][0] + t * 16;          // row8*128 + u8*16
  uchar* dW = &lsW[0][0] + t * 16;
  auto stage = [&](int s) {
    uint32_t o = (uint32_t)(s & 3) * 8192u;
    gload16(pA, dA + o);
    gload16(pW, dW + o);
    pA += 128; pW += 128;
  };

  uint32_t aB = lds_off(lsA), wB = lds_off(lsW);
  uint32_t adA[2], adW;
#pragma unroll
  for (int mt = 0; mt < 2; ++mt) {
    int ra = wm * 32 + mt * 16 + l16;
    adA[mt] = aB + (uint32_t)ra * 128u
            + (uint32_t)((((lg >> 1) ^ ((ra >> 1) & 7)) * 16) + (lg & 1) * 8);
  }
  {
    int rw = wn * 16 + l16;
    adW = wB + (uint32_t)rw * 128u
        + (uint32_t)((((lg >> 1) ^ ((rw >> 1) & 7)) * 16) + (lg & 1) * 8);
  }

  auto compute = [&](int i) {
    uint32_t off = (uint32_t)(i & 3) * 8192u;
    uint32_t A0 = adA[0] + off, A1 = adA[1] + off, B0 = adW + off;
    long a0v0 = dsr64(A0);         long a1v0 = dsr64(A1);         // h0 ks0
    long b0v0 = dsr64(B0);
    long a0v1 = dsr64(A0 ^ 32u);   long a1v1 = dsr64(A1 ^ 32u);   // h0 ks1
    long b0v1 = dsr64(B0 ^ 32u);
    long a0v2 = dsr64(A0 ^ 64u);   long a1v2 = dsr64(A1 ^ 64u);   // h1 ks0
    long b0v2 = dsr64(B0 ^ 64u);
    long a0v3 = dsr64(A0 ^ 96u);   long a1v3 = dsr64(A1 ^ 96u);   // h1 ks1
    long b0v3 = dsr64(B0 ^ 96u);
    asm volatile("s_waitcnt lgkmcnt(0)" ::: "memory");
    __builtin_amdgcn_sched_barrier(0);
    __builtin_amdgcn_s_setprio(1);
    acc[0] = __builtin_amdgcn_mfma_f32_16x16x32_fp8_fp8(a0v0, b0v0, acc[0], 0, 0, 0);
    acc[1] = __builtin_amdgcn_mfma_f32_16x16x32_fp8_fp8(a1v0, b0v0, acc[1], 0, 0, 0);
    acc[0] = __builtin_amdgcn_mfma_f32_16x16x32_fp8_fp8(a0v1, b0v1, acc[0], 0, 0, 0);
    acc[1] = __builtin_amdgcn_mfma_f32_16x16x32_fp8_fp8(a1v1, b0v1, acc[1], 0, 0, 0);
    acc[0] = __builtin_amdgcn_mfma_f32_16x16x32_fp8_fp8(a0v2, b0v2, acc[0], 0, 0, 0);
    acc[1] = __builtin_amdgcn_mfma_f32_16x16x32_fp8_fp8(a1v2, b0v2, acc[1], 0, 0, 0);
    acc[0] = __builtin_amdgcn_mfma_f32_16x16x32_fp8_fp8(a0v3, b0v3, acc[0], 0, 0, 0);
    acc[1] = __builtin_amdgcn_mfma_f32_16x16x32_fp8_fp8(a1v3, b0v3, acc[1], 0, 0, 0);
    __builtin_amdgcn_s_setprio(0);
  };

  const int nIter = 32;
  stage(0); stage(1); stage(2);
  for (int i = 0; i < nIter - 3; ++i) {
    asm volatile("s_waitcnt vmcnt(4)" ::: "memory");
    __builtin_amdgcn_s_barrier();
    stage(i + 3);
    compute(i);
  }
  asm volatile("s_waitcnt vmcnt(4)" ::: "memory");
  __builtin_amdgcn_s_barrier();
  compute(nIter - 3);
  asm volatile("s_waitcnt vmcnt(2)" ::: "memory");
  __builtin_amdgcn_s_barrier();
  compute(nIter - 2);
  asm volatile("s_waitcnt vmcnt(0)" ::: "memory");
  __builtin_amdgcn_s_barrier();
  compute(nIter - 1);

#pragma unroll
  for (int mt = 0; mt < 2; ++mt) {
    int nn = n0 + wn * 16 + l16;
#pragma unroll
    for (int r = 0; r < 4; ++r) {
      int b = mh * 64 + wm * 32 + mt * 16 + lg * 4 + r;
      float av = acc[mt][r];
      if (isA) {
        if (nn < 2048) {            // mode 0: eg0 (+ zd update)
          size_t idx = (size_t)b * D0 + nn;
          float zo = c.zd[idx]; float zn = zo - 0.1f * zo + c.x[idx];
          c.zd[idx] = zn;
          c.eg0_bf[idx] = (__bf16)(0.5f * (zn - av));
        } else {                    // mode 2: ed2
          size_t idx = (size_t)b * D2 + (nn - 2048);
          c.ed2_bf[idx] = (__bf16)(0.5f * (c.tr2[idx] - av));
        }
      } else {
        if (nn < 4096) {            // mode 1: eg1
          size_t idx = (size_t)b * D1 + nn;
          c.eg1_bf[idx] = (__bf16)(0.5f * (c.tr1[idx] - av));
        } else {                    // mode 3: ed3 (+ zl update, output)
          size_t idx = (size_t)b * D3 + (nn - 4096);
          float zo = c.zl[idx]; float zn = zo - 0.1f * zo + c.y[idx];
          c.zl[idx] = zn;
          float e = 0.5f * (zn - av);
          c.out[idx] = e; c.ed3_bf[idx] = (__bf16)e;
        }
      }
    }
  }
}

// ================= precomp (bf16 DMA engine, runs once) =================

__global__ __launch_bounds__(256, 2) void precomp_v6(Ctx c) {
  __shared__ __align__(16) __bf16 lsA[4][4096];
  __shared__ __align__(16) __bf16 lsW[4][2048];
  int t = threadIdx.x, w = t >> 6, l = t & 63;
  int l16 = l & 15, lg = l >> 4, wm = w >> 1, wn = w & 1;
  int n0 = blockIdx.x * 32, mh = blockIdx.y;
  f32x4 acc[2];
  f32x4 z4 = {0.f, 0.f, 0.f, 0.f};
  acc[0] = z4; acc[1] = z4;

  Seg segs[2]; int nIter, N; float* outp;
  if (blockIdx.z == 0) {
    segs[0] = { c.x_bf + (size_t)mh * 64 * D0, (unsigned)D0, c.V0n + (size_t)n0 * D0, (unsigned)D0, 32 };
    nIter = 32; N = D1; outp = c.xV0T;
  } else {
    segs[0] = { c.y_bf + (size_t)mh * 64 * D3, (unsigned)D3, c.W2n + (size_t)n0 * D3, (unsigned)D3, 8 };
    nIter = 8; N = D2; outp = c.yW2T;
  }
  segs[1] = segs[0];

  run_gemm(segs, nIter, &lsA[0][0], &lsW[0][0], t, wm, wn, l16, lg, acc);

  int n = n0 + wn * 16 + l16;
#pragma unroll
  for (int mt = 0; mt < 2; ++mt)
#pragma unroll
    for (int r = 0; r < 4; ++r) {
      int b = mh * 64 + wm * 32 + mt * 16 + lg * 4 + r;
      outp[(size_t)b * N + n] = acc[mt][r];
    }
}

// ================= one-shot prep (2 tiles/block; fp8 transposed weights) =================
// g ranges: W0 [0,1024) W1 [1024,3072) V1 [3072,5120) V2 [5120,5376)
//           V0 [5376,6400) W2 [6400,6656)

__global__ __launch_bounds__(256) void wprep_kernel(Ctx c, int g0) {
  __shared__ float ls[2][64][65];
  int g = blockIdx.x + g0;
  const float* src; uchar* t8 = nullptr; uchar* n8 = nullptr; __bf16* nb = nullptr; int R, C;
  if (g < 1024)       { src = c.W0; n8 = c.WA8;                         t8 = c.W0t8; R = D0; C = D1; }
  else if (g < 3072)  { g -= 1024;  src = c.W1; n8 = c.WB8;             t8 = c.W1t8; R = D1; C = D2; }
  else if (g < 5120)  { g -= 3072;  src = c.V1; n8 = c.WA8 + (size_t)2048 * 4096; t8 = c.V1t8; R = D2; C = D1; }
  else if (g < 5376)  { g -= 5120;  src = c.V2; n8 = c.WB8 + (size_t)4096 * 4096; t8 = c.V2t8; R = D3; C = D2; }
  else if (g < 6400)  { g -= 5376;  src = c.V0; nb = c.V0n; R = D1; C = D0; }
  else                { g -= 6400;  src = c.W2; nb = c.W2n; R = D2; C = D3; }
  int tpr = C / 128;
  int r0 = (g / tpr) * 64, c0 = (g % tpr) * 128;
  int t = threadIdx.x, r = t >> 2, q = t & 3;

  const float* base = src + (size_t)(r0 + r) * C + c0 + q * 16;
  float4 vv[2][4];
#pragma unroll
  for (int h = 0; h < 2; ++h)
#pragma unroll
    for (int i = 0; i < 4; ++i)
      vv[h][i] = reinterpret_cast<const float4*>(base + h * 64)[i];

  if (n8) {
#pragma unroll
    for (int h = 0; h < 2; ++h) {
      int pk[4];
#pragma unroll
      for (int i = 0; i < 4; i++) {
        float4 v = vv[h][i];
        ls[h][r][q * 16 + i * 4 + 0] = v.x; ls[h][r][q * 16 + i * 4 + 1] = v.y;
        ls[h][r][q * 16 + i * 4 + 2] = v.z; ls[h][r][q * 16 + i * 4 + 3] = v.w;
        int wd = __builtin_amdgcn_cvt_pk_fp8_f32(v.x, v.y, 0, false);
        wd = __builtin_amdgcn_cvt_pk_fp8_f32(v.z, v.w, wd, true);
        pk[i] = wd;
      }
      int4 pv; pv.x = pk[0]; pv.y = pk[1]; pv.z = pk[2]; pv.w = pk[3];
      *reinterpret_cast<int4*>(n8 + (size_t)(r0 + r) * C + c0 + h * 64 + q * 16) = pv;
    }
    __syncthreads();
    // transposed fp8: 16 column-elems -> 16 fp8 bytes (one int4)
#pragma unroll
    for (int h = 0; h < 2; ++h) {
      int pk[4];
#pragma unroll
      for (int i = 0; i < 4; i++) {
        float f0 = ls[h][q * 16 + i * 4 + 0][r];
        float f1 = ls[h][q * 16 + i * 4 + 1][r];
        float f2 = ls[h][q * 16 + i * 4 + 2][r];
        float f3 = ls[h][q * 16 + i * 4 + 3][r];
        int wd = __builtin_amdgcn_cvt_pk_fp8_f32(f0, f1, 0, false);
        wd = __builtin_amdgcn_cvt_pk_fp8_f32(f2, f3, wd, true);
        pk[i] = wd;
      }
      // wait: transposed row is the COLUMN index; elems along original rows
      int4 pv; pv.x = pk[0]; pv.y = pk[1]; pv.z = pk[2]; pv.w = pk[3];
      *reinterpret_cast<int4*>(t8 + (size_t)(c0 + h * 64 + r) * R + r0 + q * 16) = pv;
    }
  } else {
#pragma unroll
    for (int h = 0; h < 2; ++h) {
      union { __bf16 hx[16]; int4 qq[2]; } uu;
#pragma unroll
      for (int i = 0; i < 4; i++) {
        float4 v = vv[h][i];
        uu.hx[i * 4 + 0] = (__bf16)v.x; uu.hx[i * 4 + 1] = (__bf16)v.y;
        uu.hx[i * 4 + 2] = (__bf16)v.z; uu.hx[i * 4 + 3] = (__bf16)v.w;
      }
      int4* dn = reinterpret_cast<int4*>(nb + (size_t)(r0 + r) * C + c0 + h * 64 + q * 16);
      dn[0] = uu.qq[0]; dn[1] = uu.qq[1];
    }
  }
}

// cast x,y -> bf16 AND step-0 "phase2" (s=tr=0): zd=x, zl=y, eg0=.5x, ed3=.5y.
__global__ __launch_bounds__(256) void castinit_kernel(Ctx c) {
  int i = blockIdx.x * 256 + threadIdx.x;
  const int NX = BB * D0 / 4;
  union { __bf16 h[4]; uint2 u; } p, q;
  if (i < NX) {
    float4 xv = reinterpret_cast<const float4*>(c.x)[i];
    reinterpret_cast<float4*>(c.zd)[i] = xv;
    p.h[0] = (__bf16)xv.x; p.h[1] = (__bf16)xv.y; p.h[2] = (__bf16)xv.z; p.h[3] = (__bf16)xv.w;
    reinterpret_cast<uint2*>(c.x_bf)[i] = p.u;
    q.h[0] = (__bf16)(0.5f * xv.x); q.h[1] = (__bf16)(0.5f * xv.y);
    q.h[2] = (__bf16)(0.5f * xv.z); q.h[3] = (__bf16)(0.5f * xv.w);
    reinterpret_cast<uint2*>(c.eg0_bf)[i] = q.u;
  } else {
    int k = i - NX;
    float4 yv = reinterpret_cast<const float4*>(c.y)[k];
    reinterpret_cast<float4*>(c.zl)[k] = yv;
    p.h[0] = (__bf16)yv.x; p.h[1] = (__bf16)yv.y; p.h[2] = (__bf16)yv.z; p.h[3] = (__bf16)yv.w;
    reinterpret_cast<uint2*>(c.y_bf)[k] = p.u;
    q.h[0] = (__bf16)(0.5f * yv.x); q.h[1] = (__bf16)(0.5f * yv.y);
    q.h[2] = (__bf16)(0.5f * yv.z); q.h[3] = (__bf16)(0.5f * yv.w);
    reinterpret_cast<uint2*>(c.ed3_bf)[k] = q.u;
  }
}

// ================= host =================

extern "C" void kernel_launch(void* const* d_in, const int* in_sizes, int n_in,
                              void* d_out, int out_size, void* d_ws, size_t ws_size,
                              hipStream_t stream) {
  Ctx c;
  c.x  = (const float*)d_in[0];
  c.y  = (const float*)d_in[1];
  c.W0 = (const float*)d_in[2];
  c.W1 = (const float*)d_in[3];
  c.W2 = (const float*)d_in[4];
  c.V0 = (const float*)d_in[5];
  c.V1 = (const float*)d_in[6];
  c.V2 = (const float*)d_in[7];
  c.out = (float*)d_out;

  char* p = (char*)d_ws;
  auto af = [&](size_t n) -> float* { float* r = (float*)p; p += ((n * 4 + 255) & ~(size_t)255); return r; };
  auto ah = [&](size_t n) -> __bf16* { __bf16* r = (__bf16*)p; p += ((n * 2 + 255) & ~(size_t)255); return r; };
  auto au = [&](size_t n) -> uchar* { uchar* r = (uchar*)p; p += ((n + 255) & ~(size_t)255); return r; };

  const size_t S1 = (size_t)BB * D1;
  // --- zero-initialized state (memset span) ---
  c.v1 = af(S1); c.j1 = af(S1); c.r1 = af(S1); c.tr1 = af(S1);
  c.v2 = af(S1); c.j2 = af(S1); c.r2 = af(S1); c.tr2 = af(S1);
  c.eg1_bf = ah(S1); c.ed2_bf = ah(S1);
  size_t zero_bytes = (size_t)(p - (char*)d_ws);
  // --- written-before-read buffers ---
  c.zd = af((size_t)BB * D0); c.zl = af((size_t)BB * D3);
  c.xV0T = af(S1); c.yW2T = af(S1);
  c.x_bf = ah((size_t)BB * D0); c.y_bf = ah((size_t)BB * D3);
  c.eg0_bf = ah((size_t)BB * D0); c.ed3_bf = ah((size_t)BB * D3);
  c.s1_f8 = au(S1); c.s2_f8 = au(S1);
  // --- weight copies ---
  c.W0t8 = au((size_t)D1 * D0); c.W1t8 = au((size_t)D2 * D1);
  c.V1t8 = au((size_t)D1 * D2); c.V2t8 = au((size_t)D2 * D3);
  c.V0n = ah((size_t)D1 * D0); c.W2n = ah((size_t)D2 * D3);
  c.WA8 = au((size_t)(D0 + D2) * 4096);   // [W0; V1] rows, K=4096
  c.WB8 = au((size_t)(D1 + D3) * 4096);   // [W1; V2] rows, K=4096

  hipMemsetAsync(d_ws, 0, zero_bytes, stream);
  castinit_kernel<<<320, 256, 0, stream>>>(c);
  // order: phase1-step1 inputs (V1t8, W0t8) written LAST -> L3-resident at step 1
  wprep_kernel<<<1536, 256, 0, stream>>>(c, 5120);    // V2 + V0 + W2
  wprep_kernel<<<2048, 256, 0, stream>>>(c, 1024);    // W1
  wprep_kernel<<<2048, 256, 0, stream>>>(c, 3072);    // V1
  wprep_kernel<<<1024, 256, 0, stream>>>(c, 0);       // W0
  precomp_v6<<<dim3(128, 2, 2), 256, 0, stream>>>(c);

  for (int s = 1; s < NSTEPS; s++) {
    phase1_v21<<<256, 512, 0, stream>>>(c, 0.5f);
    phase2_v18<<<dim3(168, 2), 512, 0, stream>>>(c);
  }
}

// Round 17
// 808.597 us; speedup vs baseline: 1.0100x; 1.0100x over previous
//
#include <hip/hip_runtime.h>

// bPC SNN forward, 16 steps, B=128, dims 2048/4096/4096/512.
// v22 (resubmit; round 16 was an infra failure - UnresponsiveContainer).
// phase1 fp8-W dequant moved OFF the critical path. v21's -25% staged
// bytes was real (cold 45->39.6us, FETCH -30%) but the 48-op cvt chain sat
// serialized between lgkmcnt(0) and MFMA -> warm +2us/step. Now: issue W
// ds_reads FIRST, then A reads; lgkmcnt(8) waits only the 4 W reads (in-order
// LDS return); sched_barrier; cvt under the A-read shadow; lgkmcnt(0); MFMA.
// Numerics identical to v21 (absmax 0.078125, passed). phase2 = v18.

#define DEVINL __device__ __forceinline__

using bf16x8 = __attribute__((ext_vector_type(8))) __bf16;
using f32x4  = __attribute__((ext_vector_type(4))) float;
using f32x2  = __attribute__((ext_vector_type(2))) float;
using i32x4  = __attribute__((ext_vector_type(4))) int;
typedef unsigned char uchar;

static constexpr int BB = 128;
static constexpr int D0 = 2048, D1 = 4096, D2 = 4096, D3 = 512;
static constexpr int NSTEPS = 16;

struct Ctx {
  const float *x, *y, *W0, *W1, *W2, *V0, *V1, *V2;
  float *v1, *j1, *r1, *tr1, *v2, *j2, *r2, *tr2;
  float *zd, *zl, *xV0T, *yW2T;
  __bf16 *x_bf, *y_bf, *eg0_bf, *eg1_bf, *ed2_bf, *ed3_bf;
  uchar *s1_f8, *s2_f8, *WA8, *WB8;            // fp8 spikes + stacked fp8 weights (phase2)
  uchar *W0t8, *W1t8, *V1t8, *V2t8;            // fp8 TRANSPOSED weights (phase1)
  __bf16 *V0n, *W2n;                           // bf16 (precomp only)
  float *out;
};

DEVINL void gload16(const void* g, void* l) {
  __builtin_amdgcn_global_load_lds(
      (const __attribute__((address_space(1))) void*)g,
      (__attribute__((address_space(3))) void*)l, 16, 0, 0);
}
DEVINL uint32_t lds_off(const void* p) {
  return (uint32_t)(uintptr_t)(__attribute__((address_space(3))) const void*)p;
}
DEVINL bf16x8 dsr128(uint32_t addr) {
  i32x4 r;
  asm volatile("ds_read_b128 %0, %1" : "=v"(r) : "v"(addr));
  return __builtin_bit_cast(bf16x8, r);
}
DEVINL long dsr64(uint32_t addr) {
  long r;
  asm volatile("ds_read_b64 %0, %1" : "=v"(r) : "v"(addr));
  return r;
}
// 8 fp8 e4m3 bytes -> 8 bf16 (exact embedding)
DEVINL bf16x8 cvtw(long v) {
  int lo = (int)(v & 0xffffffffL);
  int hi = (int)(((unsigned long long)v) >> 32);
  f32x2 p0 = __builtin_amdgcn_cvt_pk_f32_fp8(lo, false);
  f32x2 p1 = __builtin_amdgcn_cvt_pk_f32_fp8(lo, true);
  f32x2 p2 = __builtin_amdgcn_cvt_pk_f32_fp8(hi, false);
  f32x2 p3 = __builtin_amdgcn_cvt_pk_f32_fp8(hi, true);
  bf16x8 r;
  r[0] = (__bf16)p0[0]; r[1] = (__bf16)p0[1];
  r[2] = (__bf16)p1[0]; r[3] = (__bf16)p1[1];
  r[4] = (__bf16)p2[0]; r[5] = (__bf16)p2[1];
  r[6] = (__bf16)p3[0]; r[7] = (__bf16)p3[1];
  return r;
}

// ================= engines =================
struct Seg { const __bf16* A; unsigned ldA; const __bf16* W; unsigned ldW; int iters; };
struct SPtr { const __bf16 *a0, *a1, *w; };
struct Seg8 { const __bf16* A; unsigned ldA; const uchar* W; unsigned ldW; int iters; };
struct SP8 { const __bf16* a; const uchar* w; };

DEVINL SPtr mkptr(const Seg& s, int t) {
  int r = t >> 3;
  int u = ((t & 7) ^ (r & 7)) * 8;
  SPtr p;
  p.a0 = s.A + (size_t)r * s.ldA + u;
  p.a1 = s.A + (size_t)(r + 32) * s.ldA + u;
  p.w  = s.W + (size_t)r * s.ldW + u;
  return p;
}
DEVINL SP8 mkptr8(const Seg8& s, int t) {
  int r = t >> 3;
  int ue = ((t & 7) ^ (r & 7)) * 8;    // elems (A, bf16, 16B)
  int ub = ((t & 7) ^ (r & 7)) * 16;   // bytes (W, fp8, 16B)
  SP8 p;
  p.a = s.A + (size_t)r * s.ldA + ue;
  p.w = s.W + (size_t)r * s.ldW + ub;
  return p;
}

// ---- BK=64 engine (precomp, 256 thr, bf16 W) ----
DEVINL void run_gemm(const Seg* segs, int nIter, __bf16* lsA, __bf16* lsW,
                     int t, int wm, int wn, int l16, int lg, f32x4* acc) {
  const int seg0it = segs[0].iters;
  SPtr p = mkptr(segs[0], t);
  int nxt = 0;
  auto stage = [&](int s) {
    __bf16* bA = lsA + (s & 3) * 4096;
    __bf16* bW = lsW + (s & 3) * 2048;
    gload16(p.a0, bA + t * 8);
    gload16(p.a1, bA + 2048 + t * 8);
    gload16(p.w,  bW + t * 8);
    p.a0 += 64; p.a1 += 64; p.w += 64;
    if (++nxt == seg0it) p = mkptr(segs[1], t);
  };

  const int x7 = l16 & 7;
  uint32_t aB = lds_off(lsA), wB = lds_off(lsW);
  uint32_t aAd[2][2], wAd[2];
#pragma unroll
  for (int mt = 0; mt < 2; ++mt)
#pragma unroll
    for (int ks = 0; ks < 2; ++ks)
      aAd[mt][ks] = aB + (uint32_t)(wm * 32 + mt * 16 + l16) * 128u
                       + (uint32_t)(((ks * 4 + lg) ^ x7) * 16);
#pragma unroll
  for (int ks = 0; ks < 2; ++ks)
    wAd[ks] = wB + (uint32_t)(wn * 16 + l16) * 128u
                 + (uint32_t)(((ks * 4 + lg) ^ x7) * 16);

  auto compute = [&](int i) {
    uint32_t oa = (uint32_t)(i & 3) * 8192u, ow = (uint32_t)(i & 3) * 4096u;
    bf16x8 a00 = dsr128(aAd[0][0] + oa);
    bf16x8 a01 = dsr128(aAd[0][1] + oa);
    bf16x8 a10 = dsr128(aAd[1][0] + oa);
    bf16x8 a11 = dsr128(aAd[1][1] + oa);
    bf16x8 b0  = dsr128(wAd[0] + ow);
    bf16x8 b1  = dsr128(wAd[1] + ow);
    asm volatile("s_waitcnt lgkmcnt(0)" ::: "memory");
    __builtin_amdgcn_sched_barrier(0);
    __builtin_amdgcn_s_setprio(1);
    acc[0] = __builtin_amdgcn_mfma_f32_16x16x32_bf16(a00, b0, acc[0], 0, 0, 0);
    acc[1] = __builtin_amdgcn_mfma_f32_16x16x32_bf16(a10, b0, acc[1], 0, 0, 0);
    acc[0] = __builtin_amdgcn_mfma_f32_16x16x32_bf16(a01, b1, acc[0], 0, 0, 0);
    acc[1] = __builtin_amdgcn_mfma_f32_16x16x32_bf16(a11, b1, acc[1], 0, 0, 0);
    __builtin_amdgcn_s_setprio(0);
  };

  stage(0); stage(1); stage(2);
  for (int i = 0; i < nIter - 3; ++i) {
    asm volatile("s_waitcnt vmcnt(6)" ::: "memory");
    __builtin_amdgcn_s_barrier();
    stage(i + 3);
    compute(i);
  }
  asm volatile("s_waitcnt vmcnt(6)" ::: "memory");
  __builtin_amdgcn_s_barrier();
  compute(nIter - 3);
  asm volatile("s_waitcnt vmcnt(3)" ::: "memory");
  __builtin_amdgcn_s_barrier();
  compute(nIter - 2);
  asm volatile("s_waitcnt vmcnt(0)" ::: "memory");
  __builtin_amdgcn_s_barrier();
  compute(nIter - 1);
}

// ---- BK=128 engine, 512 threads, fp8 W (phase1 v22) ----
// compute order: 4x dsr64 (W) FIRST, 8x dsr128 (A); lgkmcnt(8) -> W done
// (in-order LDS return); sched_barrier; cvt W under A-read shadow;
// lgkmcnt(0); MFMA. Dequant latency hidden.
DEVINL void run_gemm128w8(const Seg8* segs, int nIter, __bf16* lsA, uchar* lsW8,
                          int t, int wm, int wn, int l16, int lg, f32x4* acc) {
  const int seg0it = segs[0].iters;   // in BK=128 units
  SP8 p = mkptr8(segs[0], t);
  int nxt = 0;
  auto stage = [&](int buf) {
    __bf16* bA = lsA + buf * 8192;
    uchar*  bW = lsW8 + buf * 8192;
    gload16(p.a,      bA + t * 8);          // K half0, rows 0..63
    gload16(p.a + 64, bA + 4096 + t * 8);   // K half1
    gload16(p.w,      bW + t * 16);         // full BK fp8 row
    p.a += 128; p.w += 128;
    if (++nxt == seg0it) p = mkptr8(segs[1], t);
  };

  const int x7 = l16 & 7;
  uint32_t aB = lds_off(lsA), wB = lds_off(lsW8);
  uint32_t aAd[2][2], wAd8[2][2];
#pragma unroll
  for (int mt = 0; mt < 2; ++mt)
#pragma unroll
    for (int ks = 0; ks < 2; ++ks)
      aAd[mt][ks] = aB + (uint32_t)(wm * 32 + mt * 16 + l16) * 128u
                       + (uint32_t)(((ks * 4 + lg) ^ x7) * 16);
  {
    int rw = wn * 16 + l16;
#pragma unroll
    for (int h = 0; h < 2; ++h)
#pragma unroll
      for (int ks = 0; ks < 2; ++ks) {
        int j = h * 4 + ks * 2 + (lg >> 1);
        wAd8[h][ks] = wB + (uint32_t)rw * 128u
                    + (uint32_t)(((j ^ (rw & 7)) * 16) + (lg & 1) * 8);
      }
  }

  auto compute = [&](int buf) {
    uint32_t oa = (uint32_t)buf * 16384u, ow = (uint32_t)buf * 8192u;
    // W reads FIRST (oldest in lgkm queue)
    long w00 = dsr64(wAd8[0][0] + ow);
    long w01 = dsr64(wAd8[0][1] + ow);
    long w10 = dsr64(wAd8[1][0] + ow);
    long w11 = dsr64(wAd8[1][1] + ow);
    // A reads after
    bf16x8 a00 = dsr128(aAd[0][0] + oa);
    bf16x8 a01 = dsr128(aAd[0][1] + oa);
    bf16x8 a10 = dsr128(aAd[1][0] + oa);
    bf16x8 a11 = dsr128(aAd[1][1] + oa);
    bf16x8 c00 = dsr128(aAd[0][0] + oa + 8192);
    bf16x8 c01 = dsr128(aAd[0][1] + oa + 8192);
    bf16x8 c10 = dsr128(aAd[1][0] + oa + 8192);
    bf16x8 c11 = dsr128(aAd[1][1] + oa + 8192);
    // wait only the 4 W reads (12 issued, <=8 outstanding => 4 oldest done)
    asm volatile("s_waitcnt lgkmcnt(8)" ::: "memory");
    __builtin_amdgcn_sched_barrier(0);
    bf16x8 b0 = cvtw(w00);     // runs under the 8 A-read shadow
    bf16x8 b1 = cvtw(w01);
    bf16x8 d0 = cvtw(w10);
    bf16x8 d1 = cvtw(w11);
    asm volatile("s_waitcnt lgkmcnt(0)" ::: "memory");
    __builtin_amdgcn_sched_barrier(0);
    __builtin_amdgcn_s_setprio(1);
    acc[0] = __builtin_amdgcn_mfma_f32_16x16x32_bf16(a00, b0, acc[0], 0, 0, 0);
    acc[1] = __builtin_amdgcn_mfma_f32_16x16x32_bf16(a10, b0, acc[1], 0, 0, 0);
    acc[0] = __builtin_amdgcn_mfma_f32_16x16x32_bf16(a01, b1, acc[0], 0, 0, 0);
    acc[1] = __builtin_amdgcn_mfma_f32_16x16x32_bf16(a11, b1, acc[1], 0, 0, 0);
    acc[0] = __builtin_amdgcn_mfma_f32_16x16x32_bf16(c00, d0, acc[0], 0, 0, 0);
    acc[1] = __builtin_amdgcn_mfma_f32_16x16x32_bf16(c10, d0, acc[1], 0, 0, 0);
    acc[0] = __builtin_amdgcn_mfma_f32_16x16x32_bf16(c01, d1, acc[0], 0, 0, 0);
    acc[1] = __builtin_amdgcn_mfma_f32_16x16x32_bf16(c11, d1, acc[1], 0, 0, 0);
    __builtin_amdgcn_s_setprio(0);
  };

  stage(0); stage(1);
  int cur = 0, nx = 2;
  for (int i = 0; i < nIter - 2; ++i) {
    asm volatile("s_waitcnt vmcnt(3)" ::: "memory");
    __builtin_amdgcn_s_barrier();
    stage(nx);
    compute(cur);
    cur = (cur == 2) ? 0 : cur + 1;
    nx  = (nx == 2) ? 0 : nx + 1;
  }
  asm volatile("s_waitcnt vmcnt(3)" ::: "memory");
  __builtin_amdgcn_s_barrier();
  compute(cur);
  cur = (cur == 2) ? 0 : cur + 1;
  asm volatile("s_waitcnt vmcnt(0)" ::: "memory");
  __builtin_amdgcn_s_barrier();
  compute(cur);
}

// ================= phase1 v22 (bf16 A x fp8 W, 64x64, 512 thr) =================

__global__ __launch_bounds__(512, 1) void phase1_v22(Ctx c, float edsc) {
  __shared__ __align__(16) __bf16 lsA[3][8192];   // 48KB
  __shared__ __align__(128) uchar lsW8[3][8192];  // 24KB
  int t = threadIdx.x, w = t >> 6, l = t & 63;
  int l16 = l & 15, lg = l >> 4, wm = w >> 2, wn = w & 3;
  int bx = blockIdx.x;
  int z = bx >> 7, idx = bx & 127;
  int mh = idx >> 6, n0 = (idx & 63) * 64;
  f32x4 acc[2];
  f32x4 z4 = {0.f, 0.f, 0.f, 0.f};
  acc[0] = z4; acc[1] = z4;

  Seg8 segs[2]; int nIter, N;
  float *v, *j, *rf, *tr; const float* aux; const __bf16* buf; uchar* sf8;
  if (z == 0) {
    segs[0] = { c.ed2_bf + (size_t)mh * 64 * D2, (unsigned)D2, c.V1t8 + (size_t)n0 * D2, (unsigned)D2, 32 };
    segs[1] = { c.eg0_bf + (size_t)mh * 64 * D0, (unsigned)D0, c.W0t8 + (size_t)n0 * D0, (unsigned)D0, 16 };
    nIter = 48; N = D1;
    v = c.v1; j = c.j1; rf = c.r1; tr = c.tr1; buf = c.eg1_bf; aux = c.xV0T; sf8 = c.s1_f8;
  } else {
    segs[0] = { c.ed3_bf + (size_t)mh * 64 * D3, (unsigned)D3, c.V2t8 + (size_t)n0 * D3, (unsigned)D3, 4 };
    segs[1] = { c.eg1_bf + (size_t)mh * 64 * D1, (unsigned)D1, c.W1t8 + (size_t)n0 * D1, (unsigned)D1, 32 };
    nIter = 36; N = D2;
    v = c.v2; j = c.j2; rf = c.r2; tr = c.tr2; buf = c.ed2_bf; aux = c.yW2T; sf8 = c.s2_f8;
  }

  run_gemm128w8(segs, nIter, &lsA[0][0], &lsW8[0][0], t, wm, wn, l16, lg, acc);

  int n = n0 + wn * 16 + l16;
#pragma unroll
  for (int mt = 0; mt < 2; ++mt) {
#pragma unroll
    for (int r = 0; r < 4; ++r) {
      int b = mh * 64 + wm * 32 + mt * 16 + lg * 4 + r;
      size_t idx2 = (size_t)b * N + n;
      float to = tr[idx2];
      float ti = acc[mt][r] - (float)buf[idx2] - edsc * (to - aux[idx2]);
      float jo = j[idx2];
      float jn = jo + 0.1f * (ti - jo);
      float ro = rf[idx2];
      float vo = v[idx2];
      bool refr = ro > 0.0f;
      float vn = refr ? vo : (vo + 0.05f * (jn - vo));
      float sp = (!refr && vn > 1.0f) ? 1.0f : 0.0f;
      if (sp != 0.0f) vn = 0.0f;
      float rn = fmaxf(ro - 1.0f, 0.0f);
      if (sp != 0.0f) rn = 2.0f;
      float tn = to - 0.05f * to + sp;
      v[idx2] = vn; j[idx2] = jn; rf[idx2] = rn; tr[idx2] = tn;
      sf8[idx2] = (sp != 0.0f) ? (uchar)0x38 : (uchar)0;  // fp8 e4m3: 1.0 / 0.0 exact
    }
  }
}

// ================= phase2 v18 (fp8, 128B segments, 512 threads / 8 waves) =================

__global__ __launch_bounds__(512, 2) void phase2_v18(Ctx c) {
  __shared__ __align__(128) uchar lsA[4][8192];
  __shared__ __align__(128) uchar lsW[4][8192];
  int t = threadIdx.x, w = t >> 6, l = t & 63;
  int l16 = l & 15, lg = l >> 4, wm = w >> 2, wn = w & 3;
  int g = blockIdx.x, mh = blockIdx.y;

  const uchar *A, *W; int n0; bool isA;
  if (g < 96) { isA = true;  A = c.s1_f8 + (size_t)mh * 64 * D1; W = c.WA8 + (size_t)g * 64 * 4096;        n0 = g * 64; }
  else        { isA = false; A = c.s2_f8 + (size_t)mh * 64 * D2; W = c.WB8 + (size_t)(g - 96) * 64 * 4096; n0 = (g - 96) * 64; }

  f32x4 acc[2];
  f32x4 z4 = {0.f, 0.f, 0.f, 0.f};
  acc[0] = z4; acc[1] = z4;

  int row8 = t >> 3, u8 = t & 7;            // row8 0..63 (512 thr)
  int su8 = (u8 ^ ((row8 >> 1) & 7)) * 16;
  const uchar* pA = A + (size_t)row8 * 4096 + su8;
  const uchar* pW = W + (size_t)row8 * 4096 + su8;
  uchar* dA = &lsA[0][0] + t * 16;          // row8*128 + u8*16
  uchar* dW = &lsW[0][0] + t * 16;
  auto stage = [&](int s) {
    uint32_t o = (uint32_t)(s & 3) * 8192u;
    gload16(pA, dA + o);
    gload16(pW, dW + o);
    pA += 128; pW += 128;
  };

  uint32_t aB = lds_off(lsA), wB = lds_off(lsW);
  uint32_t adA[2], adW;
#pragma unroll
  for (int mt = 0; mt < 2; ++mt) {
    int ra = wm * 32 + mt * 16 + l16;
    adA[mt] = aB + (uint32_t)ra * 128u
            + (uint32_t)((((lg >> 1) ^ ((ra >> 1) & 7)) * 16) + (lg & 1) * 8);
  }
  {
    int rw = wn * 16 + l16;
    adW = wB + (uint32_t)rw * 128u
        + (uint32_t)((((lg >> 1) ^ ((rw >> 1) & 7)) * 16) + (lg & 1) * 8);
  }

  auto compute = [&](int i) {
    uint32_t off = (uint32_t)(i & 3) * 8192u;
    uint32_t A0 = adA[0] + off, A1 = adA[1] + off, B0 = adW + off;
    long a0v0 = dsr64(A0);         long a1v0 = dsr64(A1);         // h0 ks0
    long b0v0 = dsr64(B0);
    long a0v1 = dsr64(A0 ^ 32u);   long a1v1 = dsr64(A1 ^ 32u);   // h0 ks1
    long b0v1 = dsr64(B0 ^ 32u);
    long a0v2 = dsr64(A0 ^ 64u);   long a1v2 = dsr64(A1 ^ 64u);   // h1 ks0
    long b0v2 = dsr64(B0 ^ 64u);
    long a0v3 = dsr64(A0 ^ 96u);   long a1v3 = dsr64(A1 ^ 96u);   // h1 ks1
    long b0v3 = dsr64(B0 ^ 96u);
    asm volatile("s_waitcnt lgkmcnt(0)" ::: "memory");
    __builtin_amdgcn_sched_barrier(0);
    __builtin_amdgcn_s_setprio(1);
    acc[0] = __builtin_amdgcn_mfma_f32_16x16x32_fp8_fp8(a0v0, b0v0, acc[0], 0, 0, 0);
    acc[1] = __builtin_amdgcn_mfma_f32_16x16x32_fp8_fp8(a1v0, b0v0, acc[1], 0, 0, 0);
    acc[0] = __builtin_amdgcn_mfma_f32_16x16x32_fp8_fp8(a0v1, b0v1, acc[0], 0, 0, 0);
    acc[1] = __builtin_amdgcn_mfma_f32_16x16x32_fp8_fp8(a1v1, b0v1, acc[1], 0, 0, 0);
    acc[0] = __builtin_amdgcn_mfma_f32_16x16x32_fp8_fp8(a0v2, b0v2, acc[0], 0, 0, 0);
    acc[1] = __builtin_amdgcn_mfma_f32_16x16x32_fp8_fp8(a1v2, b0v2, acc[1], 0, 0, 0);
    acc[0] = __builtin_amdgcn_mfma_f32_16x16x32_fp8_fp8(a0v3, b0v3, acc[0], 0, 0, 0);
    acc[1] = __builtin_amdgcn_mfma_f32_16x16x32_fp8_fp8(a1v3, b0v3, acc[1], 0, 0, 0);
    __builtin_amdgcn_s_setprio(0);
  };

  const int nIter = 32;
  stage(0); stage(1); stage(2);
  for (int i = 0; i < nIter - 3; ++i) {
    asm volatile("s_waitcnt vmcnt(4)" ::: "memory");
    __builtin_amdgcn_s_barrier();
    stage(i + 3);
    compute(i);
  }
  asm volatile("s_waitcnt vmcnt(4)" ::: "memory");
  __builtin_amdgcn_s_barrier();
  compute(nIter - 3);
  asm volatile("s_waitcnt vmcnt(2)" ::: "memory");
  __builtin_amdgcn_s_barrier();
  compute(nIter - 2);
  asm volatile("s_waitcnt vmcnt(0)" ::: "memory");
  __builtin_amdgcn_s_barrier();
  compute(nIter - 1);

#pragma unroll
  for (int mt = 0; mt < 2; ++mt) {
    int nn = n0 + wn * 16 + l16;
#pragma unroll
    for (int r = 0; r < 4; ++r) {
      int b = mh * 64 + wm * 32 + mt * 16 + lg * 4 + r;
      float av = acc[mt][r];
      if (isA) {
        if (nn < 2048) {            // mode 0: eg0 (+ zd update)
          size_t idx = (size_t)b * D0 + nn;
          float zo = c.zd[idx]; float zn = zo - 0.1f * zo + c.x[idx];
          c.zd[idx] = zn;
          c.eg0_bf[idx] = (__bf16)(0.5f * (zn - av));
        } else {                    // mode 2: ed2
          size_t idx = (size_t)b * D2 + (nn - 2048);
          c.ed2_bf[idx] = (__bf16)(0.5f * (c.tr2[idx] - av));
        }
      } else {
        if (nn < 4096) {            // mode 1: eg1
          size_t idx = (size_t)b * D1 + nn;
          c.eg1_bf[idx] = (__bf16)(0.5f * (c.tr1[idx] - av));
        } else {                    // mode 3: ed3 (+ zl update, output)
          size_t idx = (size_t)b * D3 + (nn - 4096);
          float zo = c.zl[idx]; float zn = zo - 0.1f * zo + c.y[idx];
          c.zl[idx] = zn;
          float e = 0.5f * (zn - av);
          c.out[idx] = e; c.ed3_bf[idx] = (__bf16)e;
        }
      }
    }
  }
}

// ================= precomp (bf16 DMA engine, runs once) =================

__global__ __launch_bounds__(256, 2) void precomp_v6(Ctx c) {
  __shared__ __align__(16) __bf16 lsA[4][4096];
  __shared__ __align__(16) __bf16 lsW[4][2048];
  int t = threadIdx.x, w = t >> 6, l = t & 63;
  int l16 = l & 15, lg = l >> 4, wm = w >> 1, wn = w & 1;
  int n0 = blockIdx.x * 32, mh = blockIdx.y;
  f32x4 acc[2];
  f32x4 z4 = {0.f, 0.f, 0.f, 0.f};
  acc[0] = z4; acc[1] = z4;

  Seg segs[2]; int nIter, N; float* outp;
  if (blockIdx.z == 0) {
    segs[0] = { c.x_bf + (size_t)mh * 64 * D0, (unsigned)D0, c.V0n + (size_t)n0 * D0, (unsigned)D0, 32 };
    nIter = 32; N = D1; outp = c.xV0T;
  } else {
    segs[0] = { c.y_bf + (size_t)mh * 64 * D3, (unsigned)D3, c.W2n + (size_t)n0 * D3, (unsigned)D3, 8 };
    nIter = 8; N = D2; outp = c.yW2T;
  }
  segs[1] = segs[0];

  run_gemm(segs, nIter, &lsA[0][0], &lsW[0][0], t, wm, wn, l16, lg, acc);

  int n = n0 + wn * 16 + l16;
#pragma unroll
  for (int mt = 0; mt < 2; ++mt)
#pragma unroll
    for (int r = 0; r < 4; ++r) {
      int b = mh * 64 + wm * 32 + mt * 16 + lg * 4 + r;
      outp[(size_t)b * N + n] = acc[mt][r];
    }
}

// ================= one-shot prep (2 tiles/block; fp8 transposed weights) =================

__global__ __launch_bounds__(256) void wprep_kernel(Ctx c, int g0) {
  __shared__ float ls[2][64][65];
  int g = blockIdx.x + g0;
  const float* src; uchar* t8 = nullptr; uchar* n8 = nullptr; __bf16* nb = nullptr; int R, C;
  if (g < 1024)       { src = c.W0; n8 = c.WA8;                         t8 = c.W0t8; R = D0; C = D1; }
  else if (g < 3072)  { g -= 1024;  src = c.W1; n8 = c.WB8;             t8 = c.W1t8; R = D1; C = D2; }
  else if (g < 5120)  { g -= 3072;  src = c.V1; n8 = c.WA8 + (size_t)2048 * 4096; t8 = c.V1t8; R = D2; C = D1; }
  else if (g < 5376)  { g -= 5120;  src = c.V2; n8 = c.WB8 + (size_t)4096 * 4096; t8 = c.V2t8; R = D3; C = D2; }
  else if (g < 6400)  { g -= 5376;  src = c.V0; nb = c.V0n; R = D1; C = D0; }
  else                { g -= 6400;  src = c.W2; nb = c.W2n; R = D2; C = D3; }
  int tpr = C / 128;
  int r0 = (g / tpr) * 64, c0 = (g % tpr) * 128;
  int t = threadIdx.x, r = t >> 2, q = t & 3;

  const float* base = src + (size_t)(r0 + r) * C + c0 + q * 16;
  float4 vv[2][4];
#pragma unroll
  for (int h = 0; h < 2; ++h)
#pragma unroll
    for (int i = 0; i < 4; ++i)
      vv[h][i] = reinterpret_cast<const float4*>(base + h * 64)[i];

  if (n8) {
#pragma unroll
    for (int h = 0; h < 2; ++h) {
      int pk[4];
#pragma unroll
      for (int i = 0; i < 4; i++) {
        float4 v = vv[h][i];
        ls[h][r][q * 16 + i * 4 + 0] = v.x; ls[h][r][q * 16 + i * 4 + 1] = v.y;
        ls[h][r][q * 16 + i * 4 + 2] = v.z; ls[h][r][q * 16 + i * 4 + 3] = v.w;
        int wd = __builtin_amdgcn_cvt_pk_fp8_f32(v.x, v.y, 0, false);
        wd = __builtin_amdgcn_cvt_pk_fp8_f32(v.z, v.w, wd, true);
        pk[i] = wd;
      }
      int4 pv; pv.x = pk[0]; pv.y = pk[1]; pv.z = pk[2]; pv.w = pk[3];
      *reinterpret_cast<int4*>(n8 + (size_t)(r0 + r) * C + c0 + h * 64 + q * 16) = pv;
    }
    __syncthreads();
    // transposed fp8: 16 column-elems -> 16 fp8 bytes (one int4)
#pragma unroll
    for (int h = 0; h < 2; ++h) {
      int pk[4];
#pragma unroll
      for (int i = 0; i < 4; i++) {
        float f0 = ls[h][q * 16 + i * 4 + 0][r];
        float f1 = ls[h][q * 16 + i * 4 + 1][r];
        float f2 = ls[h][q * 16 + i * 4 + 2][r];
        float f3 = ls[h][q * 16 + i * 4 + 3][r];
        int wd = __builtin_amdgcn_cvt_pk_fp8_f32(f0, f1, 0, false);
        wd = __builtin_amdgcn_cvt_pk_fp8_f32(f2, f3, wd, true);
        pk[i] = wd;
      }
      int4 pv; pv.x = pk[0]; pv.y = pk[1]; pv.z = pk[2]; pv.w = pk[3];
      *reinterpret_cast<int4*>(t8 + (size_t)(c0 + h * 64 + r) * R + r0 + q * 16) = pv;
    }
  } else {
#pragma unroll
    for (int h = 0; h < 2; ++h) {
      union { __bf16 hx[16]; int4 qq[2]; } uu;
#pragma unroll
      for (int i = 0; i < 4; i++) {
        float4 v = vv[h][i];
        uu.hx[i * 4 + 0] = (__bf16)v.x; uu.hx[i * 4 + 1] = (__bf16)v.y;
        uu.hx[i * 4 + 2] = (__bf16)v.z; uu.hx[i * 4 + 3] = (__bf16)v.w;
      }
      int4* dn = reinterpret_cast<int4*>(nb + (size_t)(r0 + r) * C + c0 + h * 64 + q * 16);
      dn[0] = uu.qq[0]; dn[1] = uu.qq[1];
    }
  }
}

// cast x,y -> bf16 AND step-0 "phase2" (s=tr=0): zd=x, zl=y, eg0=.5x, ed3=.5y.
__global__ __launch_bounds__(256) void castinit_kernel(Ctx c) {
  int i = blockIdx.x * 256 + threadIdx.x;
  const int NX = BB * D0 / 4;
  union { __bf16 h[4]; uint2 u; } p, q;
  if (i < NX) {
    float4 xv = reinterpret_cast<const float4*>(c.x)[i];
    reinterpret_cast<float4*>(c.zd)[i] = xv;
    p.h[0] = (__bf16)xv.x; p.h[1] = (__bf16)xv.y; p.h[2] = (__bf16)xv.z; p.h[3] = (__bf16)xv.w;
    reinterpret_cast<uint2*>(c.x_bf)[i] = p.u;
    q.h[0] = (__bf16)(0.5f * xv.x); q.h[1] = (__bf16)(0.5f * xv.y);
    q.h[2] = (__bf16)(0.5f * xv.z); q.h[3] = (__bf16)(0.5f * xv.w);
    reinterpret_cast<uint2*>(c.eg0_bf)[i] = q.u;
  } else {
    int k = i - NX;
    float4 yv = reinterpret_cast<const float4*>(c.y)[k];
    reinterpret_cast<float4*>(c.zl)[k] = yv;
    p.h[0] = (__bf16)yv.x; p.h[1] = (__bf16)yv.y; p.h[2] = (__bf16)yv.z; p.h[3] = (__bf16)yv.w;
    reinterpret_cast<uint2*>(c.y_bf)[k] = p.u;
    q.h[0] = (__bf16)(0.5f * yv.x); q.h[1] = (__bf16)(0.5f * yv.y);
    q.h[2] = (__bf16)(0.5f * yv.z); q.h[3] = (__bf16)(0.5f * yv.w);
    reinterpret_cast<uint2*>(c.ed3_bf)[k] = q.u;
  }
}

// ================= host =================

extern "C" void kernel_launch(void* const* d_in, const int* in_sizes, int n_in,
                              void* d_out, int out_size, void* d_ws, size_t ws_size,
                              hipStream_t stream) {
  Ctx c;
  c.x  = (const float*)d_in[0];
  c.y  = (const float*)d_in[1];
  c.W0 = (const float*)d_in[2];
  c.W1 = (const float*)d_in[3];
  c.W2 = (const float*)d_in[4];
  c.V0 = (const float*)d_in[5];
  c.V1 = (const float*)d_in[6];
  c.V2 = (const float*)d_in[7];
  c.out = (float*)d_out;

  char* p = (char*)d_ws;
  auto af = [&](size_t n) -> float* { float* r = (float*)p; p += ((n * 4 + 255) & ~(size_t)255); return r; };
  auto ah = [&](size_t n) -> __bf16* { __bf16* r = (__bf16*)p; p += ((n * 2 + 255) & ~(size_t)255); return r; };
  auto au = [&](size_t n) -> uchar* { uchar* r = (uchar*)p; p += ((n + 255) & ~(size_t)255); return r; };

  const size_t S1 = (size_t)BB * D1;
  // --- zero-initialized state (memset span) ---
  c.v1 = af(S1); c.j1 = af(S1); c.r1 = af(S1); c.tr1 = af(S1);
  c.v2 = af(S1); c.j2 = af(S1); c.r2 = af(S1); c.tr2 = af(S1);
  c.eg1_bf = ah(S1); c.ed2_bf = ah(S1);
  size_t zero_bytes = (size_t)(p - (char*)d_ws);
  // --- written-before-read buffers ---
  c.zd = af((size_t)BB * D0); c.zl = af((size_t)BB * D3);
  c.xV0T = af(S1); c.yW2T = af(S1);
  c.x_bf = ah((size_t)BB * D0); c.y_bf = ah((size_t)BB * D3);
  c.eg0_bf = ah((size_t)BB * D0); c.ed3_bf = ah((size_t)BB * D3);
  c.s1_f8 = au(S1); c.s2_f8 = au(S1);
  // --- weight copies ---
  c.W0t8 = au((size_t)D1 * D0); c.W1t8 = au((size_t)D2 * D1);
  c.V1t8 = au((size_t)D1 * D2); c.V2t8 = au((size_t)D2 * D3);
  c.V0n = ah((size_t)D1 * D0); c.W2n = ah((size_t)D2 * D3);
  c.WA8 = au((size_t)(D0 + D2) * 4096);   // [W0; V1] rows, K=4096
  c.WB8 = au((size_t)(D1 + D3) * 4096);   // [W1; V2] rows, K=4096

  hipMemsetAsync(d_ws, 0, zero_bytes, stream);
  castinit_kernel<<<320, 256, 0, stream>>>(c);
  // order: phase1-step1 inputs (V1t8, W0t8) written LAST -> L3-resident at step 1
  wprep_kernel<<<1536, 256, 0, stream>>>(c, 5120);    // V2 + V0 + W2
  wprep_kernel<<<2048, 256, 0, stream>>>(c, 1024);    // W1
  wprep_kernel<<<2048, 256, 0, stream>>>(c, 3072);    // V1
  wprep_kernel<<<1024, 256, 0, stream>>>(c, 0);       // W0
  precomp_v6<<<dim3(128, 2, 2), 256, 0, stream>>>(c);

  for (int s = 1; s < NSTEPS; s++) {
    phase1_v22<<<256, 512, 0, stream>>>(c, 0.5f);
    phase2_v18<<<dim3(168, 2), 512, 0, stream>>>(c);
  }
}

// Round 18
// 790.686 us; speedup vs baseline: 1.0329x; 1.0227x over previous
//
#include <hip/hip_runtime.h>

// bPC SNN forward, 16 steps, B=128, dims 2048/4096/4096/512.
// v23 = v20 revert (best proven: 790.8us, absmax 0.0625). The fp8-W branch
// (v21/v22) is net-negative: the 48-op dequant chain costs shared VALU issue
// bandwidth that reordering can't hide; closed. v20 = phase1_v17 (bf16 W,
// 64x64, 512thr), phase2_v18 (fp8, 128B segments, 512thr), wprep 2-tile.
// Both phases sit on the measured ~30-40 B/cyc per-CU LDS-DMA ingress wall.

#define DEVINL __device__ __forceinline__

using bf16x8 = __attribute__((ext_vector_type(8))) __bf16;
using f32x4  = __attribute__((ext_vector_type(4))) float;
using i32x4  = __attribute__((ext_vector_type(4))) int;
typedef unsigned char uchar;

static constexpr int BB = 128;
static constexpr int D0 = 2048, D1 = 4096, D2 = 4096, D3 = 512;
static constexpr int NSTEPS = 16;

struct Ctx {
  const float *x, *y, *W0, *W1, *W2, *V0, *V1, *V2;
  float *v1, *j1, *r1, *tr1, *v2, *j2, *r2, *tr2;
  float *zd, *zl, *xV0T, *yW2T;
  __bf16 *x_bf, *y_bf, *eg0_bf, *eg1_bf, *ed2_bf, *ed3_bf;
  uchar *s1_f8, *s2_f8, *WA8, *WB8;      // fp8 spikes + stacked fp8 weights
  __bf16 *W0t, *W1t, *V1t, *V2t, *V0n, *W2n;
  float *out;
};

DEVINL void gload16(const void* g, void* l) {
  __builtin_amdgcn_global_load_lds(
      (const __attribute__((address_space(1))) void*)g,
      (__attribute__((address_space(3))) void*)l, 16, 0, 0);
}
DEVINL uint32_t lds_off(const void* p) {
  return (uint32_t)(uintptr_t)(__attribute__((address_space(3))) const void*)p;
}
DEVINL bf16x8 dsr128(uint32_t addr) {
  i32x4 r;
  asm volatile("ds_read_b128 %0, %1" : "=v"(r) : "v"(addr));
  return __builtin_bit_cast(bf16x8, r);
}
DEVINL long dsr64(uint32_t addr) {
  long r;
  asm volatile("ds_read_b64 %0, %1" : "=v"(r) : "v"(addr));
  return r;
}

// ================= bf16 engines =================
struct Seg { const __bf16* A; unsigned ldA; const __bf16* W; unsigned ldW; int iters; };
struct SPtr { const __bf16 *a0, *a1, *w; };
struct SPtrW { const __bf16 *a, *w; };

DEVINL SPtr mkptr(const Seg& s, int t) {
  int r = t >> 3;
  int u = ((t & 7) ^ (r & 7)) * 8;
  SPtr p;
  p.a0 = s.A + (size_t)r * s.ldA + u;
  p.a1 = s.A + (size_t)(r + 32) * s.ldA + u;
  p.w  = s.W + (size_t)r * s.ldW + u;
  return p;
}
DEVINL SPtrW mkptrw(const Seg& s, int t) {
  int r = t >> 3;
  int u = ((t & 7) ^ (r & 7)) * 8;
  SPtrW p;
  p.a = s.A + (size_t)r * s.ldA + u;
  p.w = s.W + (size_t)r * s.ldW + u;
  return p;
}

// ---- BK=64 engine (precomp, 256 thr) ----
DEVINL void run_gemm(const Seg* segs, int nIter, __bf16* lsA, __bf16* lsW,
                     int t, int wm, int wn, int l16, int lg, f32x4* acc) {
  const int seg0it = segs[0].iters;
  SPtr p = mkptr(segs[0], t);
  int nxt = 0;
  auto stage = [&](int s) {
    __bf16* bA = lsA + (s & 3) * 4096;
    __bf16* bW = lsW + (s & 3) * 2048;
    gload16(p.a0, bA + t * 8);
    gload16(p.a1, bA + 2048 + t * 8);
    gload16(p.w,  bW + t * 8);
    p.a0 += 64; p.a1 += 64; p.w += 64;
    if (++nxt == seg0it) p = mkptr(segs[1], t);
  };

  const int x7 = l16 & 7;
  uint32_t aB = lds_off(lsA), wB = lds_off(lsW);
  uint32_t aAd[2][2], wAd[2];
#pragma unroll
  for (int mt = 0; mt < 2; ++mt)
#pragma unroll
    for (int ks = 0; ks < 2; ++ks)
      aAd[mt][ks] = aB + (uint32_t)(wm * 32 + mt * 16 + l16) * 128u
                       + (uint32_t)(((ks * 4 + lg) ^ x7) * 16);
#pragma unroll
  for (int ks = 0; ks < 2; ++ks)
    wAd[ks] = wB + (uint32_t)(wn * 16 + l16) * 128u
                 + (uint32_t)(((ks * 4 + lg) ^ x7) * 16);

  auto compute = [&](int i) {
    uint32_t oa = (uint32_t)(i & 3) * 8192u, ow = (uint32_t)(i & 3) * 4096u;
    bf16x8 a00 = dsr128(aAd[0][0] + oa);
    bf16x8 a01 = dsr128(aAd[0][1] + oa);
    bf16x8 a10 = dsr128(aAd[1][0] + oa);
    bf16x8 a11 = dsr128(aAd[1][1] + oa);
    bf16x8 b0  = dsr128(wAd[0] + ow);
    bf16x8 b1  = dsr128(wAd[1] + ow);
    asm volatile("s_waitcnt lgkmcnt(0)" ::: "memory");
    __builtin_amdgcn_sched_barrier(0);
    __builtin_amdgcn_s_setprio(1);
    acc[0] = __builtin_amdgcn_mfma_f32_16x16x32_bf16(a00, b0, acc[0], 0, 0, 0);
    acc[1] = __builtin_amdgcn_mfma_f32_16x16x32_bf16(a10, b0, acc[1], 0, 0, 0);
    acc[0] = __builtin_amdgcn_mfma_f32_16x16x32_bf16(a01, b1, acc[0], 0, 0, 0);
    acc[1] = __builtin_amdgcn_mfma_f32_16x16x32_bf16(a11, b1, acc[1], 0, 0, 0);
    __builtin_amdgcn_s_setprio(0);
  };

  stage(0); stage(1); stage(2);
  for (int i = 0; i < nIter - 3; ++i) {
    asm volatile("s_waitcnt vmcnt(6)" ::: "memory");
    __builtin_amdgcn_s_barrier();
    stage(i + 3);
    compute(i);
  }
  asm volatile("s_waitcnt vmcnt(6)" ::: "memory");
  __builtin_amdgcn_s_barrier();
  compute(nIter - 3);
  asm volatile("s_waitcnt vmcnt(3)" ::: "memory");
  __builtin_amdgcn_s_barrier();
  compute(nIter - 2);
  asm volatile("s_waitcnt vmcnt(0)" ::: "memory");
  __builtin_amdgcn_s_barrier();
  compute(nIter - 1);
}

// ---- BK=128 engine, 512 threads (phase1 v17) ----
DEVINL void run_gemm128w(const Seg* segs, int nIter, __bf16* lsA, __bf16* lsW,
                         int t, int wm, int wn, int l16, int lg, f32x4* acc) {
  const int seg0it = segs[0].iters;   // in BK=128 units
  SPtrW p = mkptrw(segs[0], t);
  int nxt = 0;
  auto stage = [&](int buf) {
    __bf16* bA = lsA + buf * 8192;     // 16KB per buffer
    __bf16* bW = lsW + buf * 8192;
    gload16(p.a,      bA + t * 8);          // K half0, rows 0..63
    gload16(p.a + 64, bA + 4096 + t * 8);   // K half1
    gload16(p.w,      bW + t * 8);          // W half0, rows 0..63
    gload16(p.w + 64, bW + 4096 + t * 8);   // W half1
    p.a += 128; p.w += 128;
    if (++nxt == seg0it) p = mkptrw(segs[1], t);
  };

  const int x7 = l16 & 7;
  uint32_t aB = lds_off(lsA), wB = lds_off(lsW);
  uint32_t aAd[2][2], wAd[2];
#pragma unroll
  for (int mt = 0; mt < 2; ++mt)
#pragma unroll
    for (int ks = 0; ks < 2; ++ks)
      aAd[mt][ks] = aB + (uint32_t)(wm * 32 + mt * 16 + l16) * 128u
                       + (uint32_t)(((ks * 4 + lg) ^ x7) * 16);
#pragma unroll
  for (int ks = 0; ks < 2; ++ks)
    wAd[ks] = wB + (uint32_t)(wn * 16 + l16) * 128u
                 + (uint32_t)(((ks * 4 + lg) ^ x7) * 16);

  auto compute = [&](int buf) {
    uint32_t oa = (uint32_t)buf * 16384u, ow = (uint32_t)buf * 16384u;
    bf16x8 a00 = dsr128(aAd[0][0] + oa);
    bf16x8 a01 = dsr128(aAd[0][1] + oa);
    bf16x8 a10 = dsr128(aAd[1][0] + oa);
    bf16x8 a11 = dsr128(aAd[1][1] + oa);
    bf16x8 b0  = dsr128(wAd[0] + ow);
    bf16x8 b1  = dsr128(wAd[1] + ow);
    bf16x8 c00 = dsr128(aAd[0][0] + oa + 8192);
    bf16x8 c01 = dsr128(aAd[0][1] + oa + 8192);
    bf16x8 c10 = dsr128(aAd[1][0] + oa + 8192);
    bf16x8 c11 = dsr128(aAd[1][1] + oa + 8192);
    bf16x8 d0  = dsr128(wAd[0] + ow + 8192);
    bf16x8 d1  = dsr128(wAd[1] + ow + 8192);
    asm volatile("s_waitcnt lgkmcnt(0)" ::: "memory");
    __builtin_amdgcn_sched_barrier(0);
    __builtin_amdgcn_s_setprio(1);
    acc[0] = __builtin_amdgcn_mfma_f32_16x16x32_bf16(a00, b0, acc[0], 0, 0, 0);
    acc[1] = __builtin_amdgcn_mfma_f32_16x16x32_bf16(a10, b0, acc[1], 0, 0, 0);
    acc[0] = __builtin_amdgcn_mfma_f32_16x16x32_bf16(a01, b1, acc[0], 0, 0, 0);
    acc[1] = __builtin_amdgcn_mfma_f32_16x16x32_bf16(a11, b1, acc[1], 0, 0, 0);
    acc[0] = __builtin_amdgcn_mfma_f32_16x16x32_bf16(c00, d0, acc[0], 0, 0, 0);
    acc[1] = __builtin_amdgcn_mfma_f32_16x16x32_bf16(c10, d0, acc[1], 0, 0, 0);
    acc[0] = __builtin_amdgcn_mfma_f32_16x16x32_bf16(c01, d1, acc[0], 0, 0, 0);
    acc[1] = __builtin_amdgcn_mfma_f32_16x16x32_bf16(c11, d1, acc[1], 0, 0, 0);
    __builtin_amdgcn_s_setprio(0);
  };

  stage(0); stage(1);
  int cur = 0, nx = 2;
  for (int i = 0; i < nIter - 2; ++i) {
    asm volatile("s_waitcnt vmcnt(4)" ::: "memory");
    __builtin_amdgcn_s_barrier();
    stage(nx);
    compute(cur);
    cur = (cur == 2) ? 0 : cur + 1;
    nx  = (nx == 2) ? 0 : nx + 1;
  }
  asm volatile("s_waitcnt vmcnt(4)" ::: "memory");
  __builtin_amdgcn_s_barrier();
  compute(cur);
  cur = (cur == 2) ? 0 : cur + 1;
  asm volatile("s_waitcnt vmcnt(0)" ::: "memory");
  __builtin_amdgcn_s_barrier();
  compute(cur);
}

// ================= phase1 v17 (bf16, 64x64, 512 threads, 8 waves/CU) =================

__global__ __launch_bounds__(512, 1) void phase1_v17(Ctx c, float edsc) {
  __shared__ __align__(16) __bf16 lsA[3][8192];   // 48KB
  __shared__ __align__(16) __bf16 lsW[3][8192];   // 48KB
  int t = threadIdx.x, w = t >> 6, l = t & 63;
  int l16 = l & 15, lg = l >> 4, wm = w >> 2, wn = w & 3;
  int bx = blockIdx.x;
  int z = bx >> 7, idx = bx & 127;
  int mh = idx >> 6, n0 = (idx & 63) * 64;
  f32x4 acc[2];
  f32x4 z4 = {0.f, 0.f, 0.f, 0.f};
  acc[0] = z4; acc[1] = z4;

  Seg segs[2]; int nIter, N;
  float *v, *j, *rf, *tr; const float* aux; const __bf16* buf; uchar* sf8;
  if (z == 0) {
    segs[0] = { c.ed2_bf + (size_t)mh * 64 * D2, (unsigned)D2, c.V1t + (size_t)n0 * D2, (unsigned)D2, 32 };
    segs[1] = { c.eg0_bf + (size_t)mh * 64 * D0, (unsigned)D0, c.W0t + (size_t)n0 * D0, (unsigned)D0, 16 };
    nIter = 48; N = D1;
    v = c.v1; j = c.j1; rf = c.r1; tr = c.tr1; buf = c.eg1_bf; aux = c.xV0T; sf8 = c.s1_f8;
  } else {
    segs[0] = { c.ed3_bf + (size_t)mh * 64 * D3, (unsigned)D3, c.V2t + (size_t)n0 * D3, (unsigned)D3, 4 };
    segs[1] = { c.eg1_bf + (size_t)mh * 64 * D1, (unsigned)D1, c.W1t + (size_t)n0 * D1, (unsigned)D1, 32 };
    nIter = 36; N = D2;
    v = c.v2; j = c.j2; rf = c.r2; tr = c.tr2; buf = c.ed2_bf; aux = c.yW2T; sf8 = c.s2_f8;
  }

  run_gemm128w(segs, nIter, &lsA[0][0], &lsW[0][0], t, wm, wn, l16, lg, acc);

  int n = n0 + wn * 16 + l16;
#pragma unroll
  for (int mt = 0; mt < 2; ++mt) {
#pragma unroll
    for (int r = 0; r < 4; ++r) {
      int b = mh * 64 + wm * 32 + mt * 16 + lg * 4 + r;
      size_t idx2 = (size_t)b * N + n;
      float to = tr[idx2];
      float ti = acc[mt][r] - (float)buf[idx2] - edsc * (to - aux[idx2]);
      float jo = j[idx2];
      float jn = jo + 0.1f * (ti - jo);
      float ro = rf[idx2];
      float vo = v[idx2];
      bool refr = ro > 0.0f;
      float vn = refr ? vo : (vo + 0.05f * (jn - vo));
      float sp = (!refr && vn > 1.0f) ? 1.0f : 0.0f;
      if (sp != 0.0f) vn = 0.0f;
      float rn = fmaxf(ro - 1.0f, 0.0f);
      if (sp != 0.0f) rn = 2.0f;
      float tn = to - 0.05f * to + sp;
      v[idx2] = vn; j[idx2] = jn; rf[idx2] = rn; tr[idx2] = tn;
      sf8[idx2] = (sp != 0.0f) ? (uchar)0x38 : (uchar)0;  // fp8 e4m3: 1.0 / 0.0 exact
    }
  }
}

// ================= phase2 v18 (fp8, 128B segments, 512 threads / 8 waves) =================

__global__ __launch_bounds__(512, 2) void phase2_v18(Ctx c) {
  __shared__ __align__(128) uchar lsA[4][8192];
  __shared__ __align__(128) uchar lsW[4][8192];
  int t = threadIdx.x, w = t >> 6, l = t & 63;
  int l16 = l & 15, lg = l >> 4, wm = w >> 2, wn = w & 3;
  int g = blockIdx.x, mh = blockIdx.y;

  const uchar *A, *W; int n0; bool isA;
  if (g < 96) { isA = true;  A = c.s1_f8 + (size_t)mh * 64 * D1; W = c.WA8 + (size_t)g * 64 * 4096;        n0 = g * 64; }
  else        { isA = false; A = c.s2_f8 + (size_t)mh * 64 * D2; W = c.WB8 + (size_t)(g - 96) * 64 * 4096; n0 = (g - 96) * 64; }

  f32x4 acc[2];
  f32x4 z4 = {0.f, 0.f, 0.f, 0.f};
  acc[0] = z4; acc[1] = z4;

  int row8 = t >> 3, u8 = t & 7;            // row8 0..63 (512 thr)
  int su8 = (u8 ^ ((row8 >> 1) & 7)) * 16;
  const uchar* pA = A + (size_t)row8 * 4096 + su8;
  const uchar* pW = W + (size_t)row8 * 4096 + su8;
  uchar* dA = &lsA[0][0] + t * 16;          // row8*128 + u8*16
  uchar* dW = &lsW[0][0] + t * 16;
  auto stage = [&](int s) {
    uint32_t o = (uint32_t)(s & 3) * 8192u;
    gload16(pA, dA + o);
    gload16(pW, dW + o);
    pA += 128; pW += 128;
  };

  uint32_t aB = lds_off(lsA), wB = lds_off(lsW);
  uint32_t adA[2], adW;
#pragma unroll
  for (int mt = 0; mt < 2; ++mt) {
    int ra = wm * 32 + mt * 16 + l16;
    adA[mt] = aB + (uint32_t)ra * 128u
            + (uint32_t)((((lg >> 1) ^ ((ra >> 1) & 7)) * 16) + (lg & 1) * 8);
  }
  {
    int rw = wn * 16 + l16;
    adW = wB + (uint32_t)rw * 128u
        + (uint32_t)((((lg >> 1) ^ ((rw >> 1) & 7)) * 16) + (lg & 1) * 8);
  }

  auto compute = [&](int i) {
    uint32_t off = (uint32_t)(i & 3) * 8192u;
    uint32_t A0 = adA[0] + off, A1 = adA[1] + off, B0 = adW + off;
    long a0v0 = dsr64(A0);         long a1v0 = dsr64(A1);         // h0 ks0
    long b0v0 = dsr64(B0);
    long a0v1 = dsr64(A0 ^ 32u);   long a1v1 = dsr64(A1 ^ 32u);   // h0 ks1
    long b0v1 = dsr64(B0 ^ 32u);
    long a0v2 = dsr64(A0 ^ 64u);   long a1v2 = dsr64(A1 ^ 64u);   // h1 ks0
    long b0v2 = dsr64(B0 ^ 64u);
    long a0v3 = dsr64(A0 ^ 96u);   long a1v3 = dsr64(A1 ^ 96u);   // h1 ks1
    long b0v3 = dsr64(B0 ^ 96u);
    asm volatile("s_waitcnt lgkmcnt(0)" ::: "memory");
    __builtin_amdgcn_sched_barrier(0);
    __builtin_amdgcn_s_setprio(1);
    acc[0] = __builtin_amdgcn_mfma_f32_16x16x32_fp8_fp8(a0v0, b0v0, acc[0], 0, 0, 0);
    acc[1] = __builtin_amdgcn_mfma_f32_16x16x32_fp8_fp8(a1v0, b0v0, acc[1], 0, 0, 0);
    acc[0] = __builtin_amdgcn_mfma_f32_16x16x32_fp8_fp8(a0v1, b0v1, acc[0], 0, 0, 0);
    acc[1] = __builtin_amdgcn_mfma_f32_16x16x32_fp8_fp8(a1v1, b0v1, acc[1], 0, 0, 0);
    acc[0] = __builtin_amdgcn_mfma_f32_16x16x32_fp8_fp8(a0v2, b0v2, acc[0], 0, 0, 0);
    acc[1] = __builtin_amdgcn_mfma_f32_16x16x32_fp8_fp8(a1v2, b0v2, acc[1], 0, 0, 0);
    acc[0] = __builtin_amdgcn_mfma_f32_16x16x32_fp8_fp8(a0v3, b0v3, acc[0], 0, 0, 0);
    acc[1] = __builtin_amdgcn_mfma_f32_16x16x32_fp8_fp8(a1v3, b0v3, acc[1], 0, 0, 0);
    __builtin_amdgcn_s_setprio(0);
  };

  const int nIter = 32;
  stage(0); stage(1); stage(2);
  for (int i = 0; i < nIter - 3; ++i) {
    asm volatile("s_waitcnt vmcnt(4)" ::: "memory");
    __builtin_amdgcn_s_barrier();
    stage(i + 3);
    compute(i);
  }
  asm volatile("s_waitcnt vmcnt(4)" ::: "memory");
  __builtin_amdgcn_s_barrier();
  compute(nIter - 3);
  asm volatile("s_waitcnt vmcnt(2)" ::: "memory");
  __builtin_amdgcn_s_barrier();
  compute(nIter - 2);
  asm volatile("s_waitcnt vmcnt(0)" ::: "memory");
  __builtin_amdgcn_s_barrier();
  compute(nIter - 1);

#pragma unroll
  for (int mt = 0; mt < 2; ++mt) {
    int nn = n0 + wn * 16 + l16;
#pragma unroll
    for (int r = 0; r < 4; ++r) {
      int b = mh * 64 + wm * 32 + mt * 16 + lg * 4 + r;
      float av = acc[mt][r];
      if (isA) {
        if (nn < 2048) {            // mode 0: eg0 (+ zd update)
          size_t idx = (size_t)b * D0 + nn;
          float zo = c.zd[idx]; float zn = zo - 0.1f * zo + c.x[idx];
          c.zd[idx] = zn;
          c.eg0_bf[idx] = (__bf16)(0.5f * (zn - av));
        } else {                    // mode 2: ed2
          size_t idx = (size_t)b * D2 + (nn - 2048);
          c.ed2_bf[idx] = (__bf16)(0.5f * (c.tr2[idx] - av));
        }
      } else {
        if (nn < 4096) {            // mode 1: eg1
          size_t idx = (size_t)b * D1 + nn;
          c.eg1_bf[idx] = (__bf16)(0.5f * (c.tr1[idx] - av));
        } else {                    // mode 3: ed3 (+ zl update, output)
          size_t idx = (size_t)b * D3 + (nn - 4096);
          float zo = c.zl[idx]; float zn = zo - 0.1f * zo + c.y[idx];
          c.zl[idx] = zn;
          float e = 0.5f * (zn - av);
          c.out[idx] = e; c.ed3_bf[idx] = (__bf16)e;
        }
      }
    }
  }
}

// ================= precomp (bf16 DMA engine, runs once) =================

__global__ __launch_bounds__(256, 2) void precomp_v6(Ctx c) {
  __shared__ __align__(16) __bf16 lsA[4][4096];
  __shared__ __align__(16) __bf16 lsW[4][2048];
  int t = threadIdx.x, w = t >> 6, l = t & 63;
  int l16 = l & 15, lg = l >> 4, wm = w >> 1, wn = w & 1;
  int n0 = blockIdx.x * 32, mh = blockIdx.y;
  f32x4 acc[2];
  f32x4 z4 = {0.f, 0.f, 0.f, 0.f};
  acc[0] = z4; acc[1] = z4;

  Seg segs[2]; int nIter, N; float* outp;
  if (blockIdx.z == 0) {
    segs[0] = { c.x_bf + (size_t)mh * 64 * D0, (unsigned)D0, c.V0n + (size_t)n0 * D0, (unsigned)D0, 32 };
    nIter = 32; N = D1; outp = c.xV0T;
  } else {
    segs[0] = { c.y_bf + (size_t)mh * 64 * D3, (unsigned)D3, c.W2n + (size_t)n0 * D3, (unsigned)D3, 8 };
    nIter = 8; N = D2; outp = c.yW2T;
  }
  segs[1] = segs[0];

  run_gemm(segs, nIter, &lsA[0][0], &lsW[0][0], t, wm, wn, l16, lg, acc);

  int n = n0 + wn * 16 + l16;
#pragma unroll
  for (int mt = 0; mt < 2; ++mt)
#pragma unroll
    for (int r = 0; r < 4; ++r) {
      int b = mh * 64 + wm * 32 + mt * 16 + lg * 4 + r;
      outp[(size_t)b * N + n] = acc[mt][r];
    }
}

// ================= one-shot prep (2 tiles/block, high-MLP) =================
// g ranges: W0 [0,1024) W1 [1024,3072) V1 [3072,5120) V2 [5120,5376)
//           V0 [5376,6400) W2 [6400,6656)

__global__ __launch_bounds__(256) void wprep_kernel(Ctx c, int g0) {
  __shared__ float ls[2][64][65];
  int g = blockIdx.x + g0;
  const float* src; __bf16* tp = nullptr; uchar* n8 = nullptr; __bf16* nb = nullptr; int R, C;
  if (g < 1024)       { src = c.W0; n8 = c.WA8;                         tp = c.W0t; R = D0; C = D1; }
  else if (g < 3072)  { g -= 1024;  src = c.W1; n8 = c.WB8;             tp = c.W1t; R = D1; C = D2; }
  else if (g < 5120)  { g -= 3072;  src = c.V1; n8 = c.WA8 + (size_t)2048 * 4096; tp = c.V1t; R = D2; C = D1; }
  else if (g < 5376)  { g -= 5120;  src = c.V2; n8 = c.WB8 + (size_t)4096 * 4096; tp = c.V2t; R = D3; C = D2; }
  else if (g < 6400)  { g -= 5376;  src = c.V0; nb = c.V0n; R = D1; C = D0; }
  else                { g -= 6400;  src = c.W2; nb = c.W2n; R = D2; C = D3; }
  int tpr = C / 128;
  int r0 = (g / tpr) * 64, c0 = (g % tpr) * 128;
  int t = threadIdx.x, r = t >> 2, q = t & 3;

  // issue ALL loads up-front (8 x float4 = 256B in flight per thread)
  const float* base = src + (size_t)(r0 + r) * C + c0 + q * 16;
  float4 vv[2][4];
#pragma unroll
  for (int h = 0; h < 2; ++h)
#pragma unroll
    for (int i = 0; i < 4; ++i)
      vv[h][i] = reinterpret_cast<const float4*>(base + h * 64)[i];

  if (n8) {
#pragma unroll
    for (int h = 0; h < 2; ++h) {
      int pk[4];
#pragma unroll
      for (int i = 0; i < 4; i++) {
        float4 v = vv[h][i];
        ls[h][r][q * 16 + i * 4 + 0] = v.x; ls[h][r][q * 16 + i * 4 + 1] = v.y;
        ls[h][r][q * 16 + i * 4 + 2] = v.z; ls[h][r][q * 16 + i * 4 + 3] = v.w;
        int wd = __builtin_amdgcn_cvt_pk_fp8_f32(v.x, v.y, 0, false);
        wd = __builtin_amdgcn_cvt_pk_fp8_f32(v.z, v.w, wd, true);
        pk[i] = wd;
      }
      int4 pv; pv.x = pk[0]; pv.y = pk[1]; pv.z = pk[2]; pv.w = pk[3];
      *reinterpret_cast<int4*>(n8 + (size_t)(r0 + r) * C + c0 + h * 64 + q * 16) = pv;
    }
    __syncthreads();
#pragma unroll
    for (int h = 0; h < 2; ++h) {
      union { __bf16 hx[16]; int4 qq[2]; } wv;
#pragma unroll
      for (int i = 0; i < 16; i++) wv.hx[i] = (__bf16)ls[h][q * 16 + i][r];
      int4* dt = reinterpret_cast<int4*>(tp + (size_t)(c0 + h * 64 + r) * R + r0 + q * 16);
      dt[0] = wv.qq[0]; dt[1] = wv.qq[1];
    }
  } else {
#pragma unroll
    for (int h = 0; h < 2; ++h) {
      union { __bf16 hx[16]; int4 qq[2]; } uu;
#pragma unroll
      for (int i = 0; i < 4; i++) {
        float4 v = vv[h][i];
        uu.hx[i * 4 + 0] = (__bf16)v.x; uu.hx[i * 4 + 1] = (__bf16)v.y;
        uu.hx[i * 4 + 2] = (__bf16)v.z; uu.hx[i * 4 + 3] = (__bf16)v.w;
      }
      int4* dn = reinterpret_cast<int4*>(nb + (size_t)(r0 + r) * C + c0 + h * 64 + q * 16);
      dn[0] = uu.qq[0]; dn[1] = uu.qq[1];
    }
  }
}

// cast x,y -> bf16 AND step-0 "phase2" (s=tr=0): zd=x, zl=y, eg0=.5x, ed3=.5y.
__global__ __launch_bounds__(256) void castinit_kernel(Ctx c) {
  int i = blockIdx.x * 256 + threadIdx.x;
  const int NX = BB * D0 / 4;
  union { __bf16 h[4]; uint2 u; } p, q;
  if (i < NX) {
    float4 xv = reinterpret_cast<const float4*>(c.x)[i];
    reinterpret_cast<float4*>(c.zd)[i] = xv;
    p.h[0] = (__bf16)xv.x; p.h[1] = (__bf16)xv.y; p.h[2] = (__bf16)xv.z; p.h[3] = (__bf16)xv.w;
    reinterpret_cast<uint2*>(c.x_bf)[i] = p.u;
    q.h[0] = (__bf16)(0.5f * xv.x); q.h[1] = (__bf16)(0.5f * xv.y);
    q.h[2] = (__bf16)(0.5f * xv.z); q.h[3] = (__bf16)(0.5f * xv.w);
    reinterpret_cast<uint2*>(c.eg0_bf)[i] = q.u;
  } else {
    int k = i - NX;
    float4 yv = reinterpret_cast<const float4*>(c.y)[k];
    reinterpret_cast<float4*>(c.zl)[k] = yv;
    p.h[0] = (__bf16)yv.x; p.h[1] = (__bf16)yv.y; p.h[2] = (__bf16)yv.z; p.h[3] = (__bf16)yv.w;
    reinterpret_cast<uint2*>(c.y_bf)[k] = p.u;
    q.h[0] = (__bf16)(0.5f * yv.x); q.h[1] = (__bf16)(0.5f * yv.y);
    q.h[2] = (__bf16)(0.5f * yv.z); q.h[3] = (__bf16)(0.5f * yv.w);
    reinterpret_cast<uint2*>(c.ed3_bf)[k] = q.u;
  }
}

// ================= host =================

extern "C" void kernel_launch(void* const* d_in, const int* in_sizes, int n_in,
                              void* d_out, int out_size, void* d_ws, size_t ws_size,
                              hipStream_t stream) {
  Ctx c;
  c.x  = (const float*)d_in[0];
  c.y  = (const float*)d_in[1];
  c.W0 = (const float*)d_in[2];
  c.W1 = (const float*)d_in[3];
  c.W2 = (const float*)d_in[4];
  c.V0 = (const float*)d_in[5];
  c.V1 = (const float*)d_in[6];
  c.V2 = (const float*)d_in[7];
  c.out = (float*)d_out;

  char* p = (char*)d_ws;
  auto af = [&](size_t n) -> float* { float* r = (float*)p; p += ((n * 4 + 255) & ~(size_t)255); return r; };
  auto ah = [&](size_t n) -> __bf16* { __bf16* r = (__bf16*)p; p += ((n * 2 + 255) & ~(size_t)255); return r; };
  auto au = [&](size_t n) -> uchar* { uchar* r = (uchar*)p; p += ((n + 255) & ~(size_t)255); return r; };

  const size_t S1 = (size_t)BB * D1;
  // --- zero-initialized state (memset span) ---
  c.v1 = af(S1); c.j1 = af(S1); c.r1 = af(S1); c.tr1 = af(S1);
  c.v2 = af(S1); c.j2 = af(S1); c.r2 = af(S1); c.tr2 = af(S1);
  c.eg1_bf = ah(S1); c.ed2_bf = ah(S1);
  size_t zero_bytes = (size_t)(p - (char*)d_ws);
  // --- written-before-read buffers ---
  c.zd = af((size_t)BB * D0); c.zl = af((size_t)BB * D3);
  c.xV0T = af(S1); c.yW2T = af(S1);
  c.x_bf = ah((size_t)BB * D0); c.y_bf = ah((size_t)BB * D3);
  c.eg0_bf = ah((size_t)BB * D0); c.ed3_bf = ah((size_t)BB * D3);
  c.s1_f8 = au(S1); c.s2_f8 = au(S1);
  // --- weight copies ---
  c.W0t = ah((size_t)D0 * D1); c.W1t = ah((size_t)D1 * D2); c.V1t = ah((size_t)D2 * D1); c.V2t = ah((size_t)D3 * D2);
  c.V0n = ah((size_t)D1 * D0); c.W2n = ah((size_t)D2 * D3);
  c.WA8 = au((size_t)(D0 + D2) * 4096);   // [W0; V1] rows, K=4096
  c.WB8 = au((size_t)(D1 + D3) * 4096);   // [W1; V2] rows, K=4096

  hipMemsetAsync(d_ws, 0, zero_bytes, stream);
  castinit_kernel<<<320, 256, 0, stream>>>(c);
  // order: phase1-step1 inputs (V1t, W0t) written LAST -> L3-resident at step 1
  wprep_kernel<<<1536, 256, 0, stream>>>(c, 5120);    // V2 + V0 + W2
  wprep_kernel<<<2048, 256, 0, stream>>>(c, 1024);    // W1
  wprep_kernel<<<2048, 256, 0, stream>>>(c, 3072);    // V1
  wprep_kernel<<<1024, 256, 0, stream>>>(c, 0);       // W0
  precomp_v6<<<dim3(128, 2, 2), 256, 0, stream>>>(c);

  for (int s = 1; s < NSTEPS; s++) {
    phase1_v17<<<256, 512, 0, stream>>>(c, 0.5f);
    phase2_v18<<<dim3(168, 2), 512, 0, stream>>>(c);
  }
}